// Round 8
// baseline (291.916 us; speedup 1.0000x reference)
//
#include <hip/hip_runtime.h>
#include <math.h>

// ---------------------------------------------------------------------------
// Prototypical network forward on MI355X.
// Round 10: per-stage boundary handling. conv_layer<MASK>: stage1 uses
// unconditional writes + edge-only row-zero pass (only 2/6 strips are edges);
// stage2 uses value-masked writes on the division-free walk (every stage2
// block is an edge block, so the zero-pass + barrier per layer was a net
// loss there -- the R9 "rest" regression). Stage1 unchanged from R9.
//   image slots: [0,160) sup | [160,320) sup flipped | [320,800) pro(sup+qry)
// ---------------------------------------------------------------------------

typedef __attribute__((ext_vector_type(8))) short bf16x8;
typedef __attribute__((ext_vector_type(8))) unsigned short u16x8;
typedef __attribute__((ext_vector_type(4))) float f32x4;
typedef unsigned short u16;
typedef unsigned int u32;

#define PIX84 (84 * 84)      // 7056
#define D     (21 * 21 * 16) // 7056
#define WF_LAYER 2560        // u16 per conv2..8 layer: 5 steps * 64 lanes * 8
#define WF_C1 (7 * WF_LAYER) // 17920: offset (u16) of conv1 A-fragments
#define WF_VAR (WF_C1 + 1024) // u16 per variant (plain / Wm-scaled)

__device__ __forceinline__ float bf2f(u16 v) {
    union { u32 i; float f; } c; c.i = ((u32)v) << 16; return c.f;
}
__device__ __forceinline__ u16 f2bf(float f) {
    union { float f; u32 i; } c; c.f = f;
    u32 r = c.i + 0x7fffu + ((c.i >> 16) & 1u);
    return (u16)(r >> 16);
}
// Native bf16 pair conversion: compiler emits v_cvt_pk_bf16_f32 (RNE).
__device__ __forceinline__ u32 pack2(float a, float b) {
    union { __bf16 h[2]; u32 u; } p;
    p.h[0] = (__bf16)a; p.h[1] = (__bf16)b;
    return p.u;
}

// 16B LDS load with only 8B alignment guarantee (ds_read2_b64).
__device__ __forceinline__ bf16x8 ld_bf16x8_a8(const char* p) {
    union { uint2 q[2]; bf16x8 v; } u;
    u.q[0] = *(const uint2*)(p);
    u.q[1] = *(const uint2*)(p + 8);
    return u.v;
}

__device__ __forceinline__ float blockReduceSum(float v) {
    __shared__ float red[8];
    #pragma unroll
    for (int o = 32; o > 0; o >>= 1) v += __shfl_down(v, o, 64);
    const int lane = threadIdx.x & 63, wid = threadIdx.x >> 6;
    __syncthreads();
    if (lane == 0) red[wid] = v;
    __syncthreads();
    float r = 0.f;
    if (threadIdx.x == 0) {
        const int nw = (blockDim.x + 63) >> 6;
        for (int i = 0; i < nw; ++i) r += red[i];
    }
    return r;
}

// Pack conv weights into MFMA A-fragment layout, two variants (v=0 plain,
// v=1 scaled by the layer's Wm factor), plus a bias table [2][8][16] f32
// (same scaling; bias seeds the accumulator in conv_layer).
// conv2..8 K=160 mapping: gg=(g>>1) tap table {m / m+5}, ci = (g&1)*8 + j.
// conv1: 2 MFMAs, k = dh*16 + dw*4 + ci (m0: dh 0/1, m1: dh 2).
__global__ void prep_weights(const float* __restrict__ k1, const float* __restrict__ k2,
                             const float* __restrict__ k3, const float* __restrict__ k4,
                             const float* __restrict__ k5, const float* __restrict__ k6,
                             const float* __restrict__ k7, const float* __restrict__ k8,
                             const float* __restrict__ b1, const float* __restrict__ b2,
                             const float* __restrict__ b3, const float* __restrict__ b4,
                             const float* __restrict__ b5, const float* __restrict__ b6,
                             const float* __restrict__ b7, const float* __restrict__ b8,
                             const float* __restrict__ Wm,
                             u16* __restrict__ wf, float* __restrict__ bias_tab)
{
    const int idx = blockIdx.x * 256 + threadIdx.x;
    if (idx < 2 * WF_VAR) {
        const int v = (idx >= WF_VAR) ? 1 : 0;
        const int r0 = idx - v * WF_VAR;
        if (r0 < WF_C1) {
            const int j = r0 & 7, lane = (r0 >> 3) & 63, r = r0 >> 9;
            const int m = r % 5, L = r / 5;
            const float* ks[7] = { k2, k3, k4, k5, k6, k7, k8 };
            const int sidx[7] = { 1, 2, 3, 7, 8, 9, 10 };
            const int co = lane & 15, g = lane >> 4;
            const int gg = g >> 1, h = g & 1;
            const int tap = gg ? (m + 5) : m;
            const int ci = h * 8 + j;
            float val = (tap < 9) ? ks[L][(tap * 16 + ci) * 16 + co] : 0.f;
            if (v) val *= Wm[sidx[L]];
            wf[idx] = f2bf(val);
        } else {
            const int t = r0 - WF_C1;
            const int j = t & 7, lane = (t >> 3) & 63, m = t >> 9;
            const int co = lane & 15, g = lane >> 4;
            const int k = g * 8 + j;
            const int dh  = (m == 0) ? (k >> 4) : 2;
            const int rem = (m == 0) ? (k & 15) : k;
            const int dw = rem >> 2, ci = rem & 3;
            float val = (rem < 12 && ci < 3) ? k1[((dh * 3 + dw) * 3 + ci) * 16 + co] : 0.f;
            if (v) val *= Wm[0];
            wf[idx] = f2bf(val);
        }
    } else if (idx < 2 * WF_VAR + 256) {
        const int t = idx - 2 * WF_VAR;
        const int v = t >> 7, L = (t >> 4) & 7, ch = t & 15;
        const float* Bs[8] = { b1, b2, b3, b4, b5, b6, b7, b8 };
        const int sm[8] = { 0, 1, 2, 3, 7, 8, 9, 10 };
        float val = Bs[L][ch];
        if (v) val *= Wm[sm[L]];
        bias_tab[t] = val;
    }
}

// One 16ch->16ch conv layer, MFMA K=160, in-place, bias-seeded accumulator.
// Division-free incremental (j,w,ra) walk (+16 px / tile).
// MASK=false: unconditional writes + caller-side row-zero pass for edges
//             (tail overflow lands in rows never read).
// MASK=true:  value-masked writes (rows outside [v0,v1) written as exact 0);
//             no zero-pass, no extra barrier.
// Per-lane-group fragment table (gg = g>>1, h = g&1):
//   gg=0: px offsets {0, 1, 2, LW, LW+1}                   (taps 0..4)
//   gg=1: px offsets {LW+2, 2LW, 2LW+1, 2LW+2, LW+2(dead)} (taps 5..8)
template <int W, int LW, int MAXT, int HALF, bool MASK>
__device__ __forceinline__ void conv_layer(char* buf, const u16* wfL,
                                           const float4 bv,
                                           int nrows, int v0, int v1,
                                           int lane, int wv)
{
    const int g = lane >> 4, col = lane & 15, gg = g >> 1, h = g & 1;
    bf16x8 wfr[5];
    #pragma unroll
    for (int s = 0; s < 5; ++s) wfr[s] = ((const bf16x8*)wfL)[s * 64 + lane];
    const int NPX = nrows * W;
    const int TC = (NPX + 15) >> 4;
    const int t0 = wv * MAXT;
    const int C0 = h * HALF + (gg ? (LW + 2)     : 0       ) * 16;
    const int C1 = h * HALF + (gg ? (2 * LW)     : 1       ) * 16;
    const int C2 = h * HALF + (gg ? (2 * LW + 1) : 2       ) * 16;
    const int C3 = h * HALF + (gg ? (2 * LW + 2) : LW      ) * 16;
    const int C4 = h * HALF + (gg ? (LW + 2)     : (LW + 1)) * 16;
    const int wb = gg * HALF + h * 8 + 16;   // write: half gg, byte h*8, col+1

    f32x4 acc[MAXT];
    {
        int px = t0 * 16 + col;
        int j  = px / W;
        int w  = px - j * W;
        int ra = (j * LW + w) * 16;
        #pragma unroll
        for (int u = 0; u < MAXT; ++u) {
            if (t0 + u < TC) {
                const char* rb = buf + ra;
                f32x4 a = { bv.x, bv.y, bv.z, bv.w };
                a = __builtin_amdgcn_mfma_f32_16x16x32_bf16(wfr[0], *(const bf16x8*)(rb + C0), a, 0, 0, 0);
                a = __builtin_amdgcn_mfma_f32_16x16x32_bf16(wfr[1], *(const bf16x8*)(rb + C1), a, 0, 0, 0);
                a = __builtin_amdgcn_mfma_f32_16x16x32_bf16(wfr[2], *(const bf16x8*)(rb + C2), a, 0, 0, 0);
                a = __builtin_amdgcn_mfma_f32_16x16x32_bf16(wfr[3], *(const bf16x8*)(rb + C3), a, 0, 0, 0);
                a = __builtin_amdgcn_mfma_f32_16x16x32_bf16(wfr[4], *(const bf16x8*)(rb + C4), a, 0, 0, 0);
                acc[u] = a;
            }
            const bool wrap = (w + 16) >= W;
            ra += wrap ? (LW + 16 - W) * 16 : 256;
            w  += wrap ? (16 - W) : 16;
        }
    }
    __syncthreads();   // all reads done before any in-place write
    {
        int px = t0 * 16 + col;
        int j  = px / W;
        int w  = px - j * W;
        int ra = (j * LW + w) * 16 + wb;
        #pragma unroll
        for (int u = 0; u < MAXT; ++u) {
            if (t0 + u < TC) {
                u32 lo, hi;
                if (MASK) {
                    const bool val = (j >= v0) && (j < v1);
                    lo = val ? pack2(acc[u][0], acc[u][1]) : 0u;
                    hi = val ? pack2(acc[u][2], acc[u][3]) : 0u;
                } else {
                    lo = pack2(acc[u][0], acc[u][1]);
                    hi = pack2(acc[u][2], acc[u][3]);
                }
                *(uint2*)(buf + ra) = make_uint2(lo, hi);
            }
            const bool wrap = (w + 16) >= W;
            ra += wrap ? (LW + 16 - W) * 16 : 256;
            w  += wrap ? (16 - W) : 16;
            j  += wrap ? 1 : 0;
        }
    }
    if (!MASK && (v0 > 0 || v1 < nrows)) {   // block-uniform: edge strips only
        __syncthreads();
        const int nzr = v0 + (nrows - v1);
        for (int i = threadIdx.x; i < nzr * LW; i += 512) {
            const int q = i / LW, c = i - q * LW;
            const int r = (q < v0) ? q : (v1 + (q - v0));
            const int P = (r * LW + c) * 16;
            *(uint4*)(buf + P) = make_uint4(0, 0, 0, 0);
            *(uint4*)(buf + HALF + P) = make_uint4(0, 0, 0, 0);
        }
    }
    __syncthreads();
}

// stage1: conv1(MFMA) + conv2/3/4(MFMA) + bn/relu/pool -> s1out (42x42x16 bf16)
// grid: img * 6 strips (7 pooled rows each). Single 20x86 LDS buffer, in-place.
#define HALF1 (20 * 86 * 16 + 16)   // 27536 B
__global__ __launch_bounds__(512) void stage1_kernel(
    const float* __restrict__ sup, const float* __restrict__ qry,
    const u16* __restrict__ wf, const float* __restrict__ bias_tab,
    const float* __restrict__ g1, const float* __restrict__ be1,
    const float* __restrict__ Wm,
    u16* __restrict__ s1out)
{
    __shared__ char buf[2 * HALF1];             // 55,072 B
    __shared__ u16 stag[(22 * 86 + 2) * 4];     // 15,152 B raw input, ch padded to 4
    const int img = blockIdx.x / 6, bb = blockIdx.x % 6;
    const int R0 = 14 * bb;              // base c4-row of this strip
    const int tid = threadIdx.x, lane = tid & 63, wv = tid >> 6;
    const bool pro = img >= 320;

    const float* src;
    bool flip = false;
    if (img < 160) src = sup + (size_t)img * (PIX84 * 3);
    else if (img < 320) { src = sup + (size_t)(img - 160) * (PIX84 * 3); flip = true; }
    else {
        const int m = img - 320;
        src = (m < 160) ? sup + (size_t)m * (PIX84 * 3)
                        : qry + (size_t)(m - 160) * (PIX84 * 3);
    }
    const u16* wfv = wf + (pro ? WF_VAR : 0);
    const float* bt = bias_tab + (pro ? 128 : 0);
    const float pre = pro ? Wm[4] : 1.f, rs = pro ? Wm[5] : 1.f;
    const float post = pro ? Wm[6] : 1.f;

    // zero border columns of conv buffer (rows 0..19, cols 0 & 85)
    for (int i = tid; i < 40; i += 512) {
        const int P = (i >> 1) * 86 + ((i & 1) ? 85 : 0);
        *(uint4*)(buf + P * 16) = make_uint4(0, 0, 0, 0);
        *(uint4*)(buf + HALF1 + P * 16) = make_uint4(0, 0, 0, 0);
    }

    // stage raw input rows R0-4 .. R0+17 as bf16, zero-padded borders.
    for (int p = tid; p < 22 * 86; p += 512) {
        const int r = p / 86, c = p - r * 86;
        const int hin = R0 - 4 + r, win = c - 1;
        u32 lo = 0, hi = 0;
        if ((unsigned)hin < 84u && (unsigned)win < 84u) {
            const int wsrc = flip ? (83 - win) : win;
            const float* ip = src + ((size_t)(hin * 84 + wsrc)) * 3;
            lo = pack2(ip[0], ip[1]);
            hi = pack2(ip[2], 0.f);
        }
        *(uint2*)((char*)stag + (size_t)p * 8) = make_uint2(lo, hi);
    }
    __syncthreads();

    const int g = lane >> 4, col = lane & 15;

    // conv1 via MFMA: 105 tiles (t = wv + 8u), incremental addresses.
    {
        const bf16x8 wA0 = ((const bf16x8*)(wfv + WF_C1))[lane];
        const bf16x8 wA1 = ((const bf16x8*)(wfv + WF_C1))[64 + lane];
        const float4 bv = *(const float4*)(bt + g * 4);   // layer-1 bias (scaled)
        const int off0 = ((g >> 1) * 86 + (g & 1) * 2) * 8;
        const int off1 = (2 * 86 + (g & 1) * 2) * 8;
        const int wbc = (g >> 1) * HALF1 + (g & 1) * 8 + 16;
        int w = wv * 16 + col, j = 0;
        if (w >= 84) { w -= 84; j = 1; }
        int sra = (j * 86 + w) * 8;
        const int trips1 = (112 - wv) >> 3;   // TC=105
        #pragma unroll
        for (int u = 0; u < 14; ++u) {
            if (u < trips1) {
                const bf16x8 B0 = ld_bf16x8_a8((const char*)stag + sra + off0);
                const bf16x8 B1 = ld_bf16x8_a8((const char*)stag + sra + off1);
                f32x4 a = { bv.x, bv.y, bv.z, bv.w };
                a = __builtin_amdgcn_mfma_f32_16x16x32_bf16(wA0, B0, a, 0, 0, 0);
                a = __builtin_amdgcn_mfma_f32_16x16x32_bf16(wA1, B1, a, 0, 0, 0);
                const u32 lo = pack2(a[0], a[1]);
                const u32 hi = pack2(a[2], a[3]);
                *(uint2*)(buf + sra * 2 + wbc) = make_uint2(lo, hi);
            }
            const bool wrap = (w + 44) >= 84;
            sra += wrap ? 1056 : 1040;        // (2*86-40)*8 : (86+44)*8
            w = wrap ? (w - 40) : (w + 44);
        }
    }
    __syncthreads();
    if (R0 == 0 || R0 == 70) {    // conv1 rows outside image -> exact zero
        const int rz = (R0 == 0) ? 0 : 17;
        for (int i = tid; i < 3 * 86; i += 512) {
            const int q = i / 86;
            const int P = ((rz + q) * 86 + (i - q * 86)) * 16;
            *(uint4*)(buf + P) = make_uint4(0, 0, 0, 0);
            *(uint4*)(buf + HALF1 + P) = make_uint4(0, 0, 0, 0);
        }
        __syncthreads();
    }

    const float4 bv2 = *(const float4*)(bt + 16 + g * 4);
    const float4 bv3 = *(const float4*)(bt + 32 + g * 4);
    const float4 bv4 = *(const float4*)(bt + 48 + g * 4);

    // valid-row windows: buf row i after layer L holds conv-row R0-3+L+i.
    conv_layer<84, 86, 12, HALF1, false>(buf, wfv,                bv2, 18,
                                  (2 - R0 > 0) ? 2 - R0 : 0, (86 - R0 < 18) ? 86 - R0 : 18, lane, wv);
    conv_layer<84, 86, 11, HALF1, false>(buf, wfv + WF_LAYER,     bv3, 16,
                                  (1 - R0 > 0) ? 1 - R0 : 0, (85 - R0 < 16) ? 85 - R0 : 16, lane, wv);
    conv_layer<84, 86, 10, HALF1, false>(buf, wfv + 2 * WF_LAYER, bv4, 14,
                                  0,                         (84 - R0 < 14) ? 84 - R0 : 14, lane, wv);

    // monotone pool: o = AR * relu(max(fma(A,mx,B), fma(A,mn,B))) — exact.
    const int hf = tid & 1;      // e&1 == tid&1 (stride 512 even)
    float Ag[8], Bg[8];
    #pragma unroll
    for (int c = 0; c < 8; ++c) {
        const int ch = hf * 8 + c;
        Ag[c] = pre * g1[ch];
        Bg[c] = pre * be1[ch];
    }
    const float AR = post * rs;
    for (int e = tid; e < 7 * 42 * 2; e += 512) {
        const int pc = (e >> 1) % 42, pr = (e >> 1) / 42;
        const char* hb = buf + hf * HALF1;
        const int P0 = (2 * pr) * 86 + (2 * pc + 1);
        const u16x8 v00 = *(const u16x8*)(hb + P0 * 16);
        const u16x8 v01 = *(const u16x8*)(hb + (P0 + 1) * 16);
        const u16x8 v10 = *(const u16x8*)(hb + (P0 + 86) * 16);
        const u16x8 v11 = *(const u16x8*)(hb + (P0 + 87) * 16);
        float o[8];
        #pragma unroll
        for (int c = 0; c < 8; ++c) {
            const float x0 = bf2f(v00[c]), x1 = bf2f(v01[c]);
            const float x2 = bf2f(v10[c]), x3 = bf2f(v11[c]);
            const float mx = fmaxf(fmaxf(fmaxf(x0, x1), x2), x3);
            const float mn = fminf(fminf(fminf(x0, x1), x2), x3);
            const float t1 = fmaf(Ag[c], mx, Bg[c]);
            const float t2 = fmaf(Ag[c], mn, Bg[c]);
            o[c] = AR * fmaxf(0.f, fmaxf(t1, t2));
        }
        uint4 ov;
        ov.x = pack2(o[0], o[1]);
        ov.y = pack2(o[2], o[3]);
        ov.z = pack2(o[4], o[5]);
        ov.w = pack2(o[6], o[7]);
        *(uint4*)(s1out + (size_t)img * 28224 +
                  ((size_t)(7 * bb + pr) * 42 + pc) * 16 + hf * 8) = ov;
    }
}

// stage2: 2 blocks per image (c8 rows [0,22) / [22,42)), stage1-style
// shrinking in-place buffer; conv5..8 + bn + pool -> z/zp (f32).
#define LW2   46
#define NR2   30
#define HALF2 (NR2 * LW2 * 16 + 16)   // 22,096 B
__global__ __launch_bounds__(512) void stage2_kernel(
    const u16* __restrict__ s1in,
    const u16* __restrict__ wf, const float* __restrict__ bias_tab,
    const float* __restrict__ g2, const float* __restrict__ be2,
    const float* __restrict__ Wm,
    float* __restrict__ z, float* __restrict__ zp)
{
    __shared__ char buf[2 * HALF2];   // 44,192 B
    const int img = blockIdx.x >> 1, hb2 = blockIdx.x & 1;
    const int nc8 = hb2 ? 20 : 22;
    const int R0in = hb2 ? 18 : -4;   // s1 row held in buf row 0
    const int tid = threadIdx.x, lane = tid & 63, wv = tid >> 6;
    const bool pro = img >= 320;
    const u16* wfv = wf + (pro ? WF_VAR : 0);
    const float* bt = bias_tab + (pro ? 128 : 0);
    const float pre = pro ? Wm[11] : 1.f, rs = pro ? Wm[12] : 1.f;
    const float post = pro ? (Wm[13] * Wm[14]) : 1.f;

    // load s1 rows R0in .. R0in+29 (zero outside image / border cols)
    const u16* ip = s1in + (size_t)img * 28224;
    for (int i = tid; i < NR2 * 44; i += 512) {
        const int r = i / 44, c = i - r * 44;
        const int gr = R0in + r;
        const int P = r * LW2 + c;
        uint4 w0 = make_uint4(0, 0, 0, 0), w1 = w0;
        if (c >= 1 && c <= 42 && gr >= 0 && gr < 42) {
            const u16* q = ip + ((size_t)(gr * 42 + (c - 1))) * 16;
            w0 = *(const uint4*)q;
            w1 = *(const uint4*)(q + 8);
        }
        *(uint4*)(buf + P * 16) = w0;
        *(uint4*)(buf + HALF2 + P * 16) = w1;
    }
    __syncthreads();

    const int g = lane >> 4;
    const float4 bv5 = *(const float4*)(bt + 64 + g * 4);
    const float4 bv6 = *(const float4*)(bt + 80 + g * 4);
    const float4 bv7 = *(const float4*)(bt + 96 + g * 4);
    const float4 bv8 = *(const float4*)(bt + 112 + g * 4);

    // buf row i after layer L (L=1..4) holds c(4+L) row R0in+i+L.
    {
        const int n1 = nc8 + 6, n2 = nc8 + 4, n3 = nc8 + 2, n4 = nc8;
        int a0, a1;
        a0 = -R0in - 1; if (a0 < 0) a0 = 0; a1 = 41 - R0in; if (a1 > n1) a1 = n1;
        conv_layer<42, LW2, 10, HALF2, true>(buf, wfv + 3 * WF_LAYER, bv5, n1, a0, a1, lane, wv);
        a0 = -R0in - 2; if (a0 < 0) a0 = 0; a1 = 40 - R0in; if (a1 > n2) a1 = n2;
        conv_layer<42, LW2, 10, HALF2, true>(buf, wfv + 4 * WF_LAYER, bv6, n2, a0, a1, lane, wv);
        a0 = -R0in - 3; if (a0 < 0) a0 = 0; a1 = 39 - R0in; if (a1 > n3) a1 = n3;
        conv_layer<42, LW2, 10, HALF2, true>(buf, wfv + 5 * WF_LAYER, bv7, n3, a0, a1, lane, wv);
        a0 = -R0in - 4; if (a0 < 0) a0 = 0; a1 = 38 - R0in; if (a1 > n4) a1 = n4;
        conv_layer<42, LW2, 10, HALF2, true>(buf, wfv + 6 * WF_LAYER, bv8, n4, a0, a1, lane, wv);
    }

    float* outp = pro ? (zp + (size_t)(img - 320) * D) : (z + (size_t)img * D);
    const int hf = tid & 1;
    float Ag[8], Bg[8];
    #pragma unroll
    for (int c = 0; c < 8; ++c) {
        const int ch = hf * 8 + c;
        Ag[c] = pre * g2[ch];
        Bg[c] = pre * be2[ch];
    }
    const float AR = post * rs;
    const int np = nc8 >> 1;
    for (int e = tid; e < np * 21 * 2; e += 512) {
        const int pc = (e >> 1) % 21, pr = (e >> 1) / 21;
        const char* hb = buf + hf * HALF2;
        const int P0 = (2 * pr) * LW2 + (2 * pc + 1);
        const u16x8 v00 = *(const u16x8*)(hb + P0 * 16);
        const u16x8 v01 = *(const u16x8*)(hb + (P0 + 1) * 16);
        const u16x8 v10 = *(const u16x8*)(hb + (P0 + LW2) * 16);
        const u16x8 v11 = *(const u16x8*)(hb + (P0 + LW2 + 1) * 16);
        float o[8];
        #pragma unroll
        for (int c = 0; c < 8; ++c) {
            const float x0 = bf2f(v00[c]), x1 = bf2f(v01[c]);
            const float x2 = bf2f(v10[c]), x3 = bf2f(v11[c]);
            const float mx = fmaxf(fmaxf(fmaxf(x0, x1), x2), x3);
            const float mn = fminf(fminf(fminf(x0, x1), x2), x3);
            const float t1 = fmaf(Ag[c], mx, Bg[c]);
            const float t2 = fmaf(Ag[c], mn, Bg[c]);
            o[c] = AR * fmaxf(0.f, fmaxf(t1, t2));
        }
        float* op = outp + ((size_t)((hb2 * 11 + pr) * 21 + pc)) * 16 + hf * 8;
        *(float4*)op = make_float4(o[0], o[1], o[2], o[3]);
        *(float4*)(op + 4) = make_float4(o[4], o[5], o[6], o[7]);
    }
}

// Pairwise (mean squared distance)^2 over z (320 f32 rows).
__global__ void pairs_kernel(const float* __restrict__ z,
                             float* __restrict__ within, float* __restrict__ cross,
                             float* __restrict__ aug)
{
    const int bid = blockIdx.x;
    const float *u, *v;
    float* dst;
    if (bid < 1280) {
        const int c = bid / 64, i = (bid % 64) / 8, j = bid % 8;
        u = z + (size_t)(c * 8 + i) * D;
        v = z + (size_t)(c * 8 + j) * D;
        dst = within + bid;
    } else if (bid < 2560) {
        const int t = bid - 1280;
        const int c = t / 64, i = (t % 64) / 8, j = t % 8;
        const int c2 = (c + 1) % 20;
        u = z + (size_t)(c * 8 + i) * D;
        v = z + (size_t)(c2 * 8 + j) * D;
        dst = cross + t;
    } else {
        const int t = bid - 2560;
        u = z + (size_t)t * D;
        v = z + (size_t)(160 + t) * D;
        dst = aug + t;
    }
    const float4* u4 = (const float4*)u;
    const float4* v4 = (const float4*)v;
    float s = 0.f;
    for (int d = threadIdx.x; d < D / 4; d += 256) {
        const float4 a = u4[d], b = v4[d];
        const float dx = a.x - b.x, dy = a.y - b.y, dz = a.z - b.z, dw = a.w - b.w;
        s += dx * dx + dy * dy + dz * dz + dw * dw;
    }
    s = blockReduceSum(s);
    if (threadIdx.x == 0) {
        const float m = s / (float)D;
        *dst = m * m;
    }
}

__global__ void protos_kernel(const float* __restrict__ zp, float* __restrict__ protos)
{
    const int idx = blockIdx.x * 256 + threadIdx.x;
    if (idx >= 20 * D) return;
    const int c = idx / D, d = idx % D;
    float s = 0.f;
    #pragma unroll
    for (int i = 0; i < 8; ++i) s += zp[(size_t)(c * 8 + i) * D + d];
    protos[idx] = s * 0.125f;
}

__global__ void dists_kernel(const float* __restrict__ zq, const float* __restrict__ protos,
                             float* __restrict__ dists)
{
    const int q = blockIdx.x / 20, c = blockIdx.x % 20;
    const float4* u4 = (const float4*)(zq + (size_t)q * D);
    const float4* v4 = (const float4*)(protos + (size_t)c * D);
    float s = 0.f;
    for (int d = threadIdx.x; d < D / 4; d += 256) {
        const float4 a = u4[d], b = v4[d];
        const float dx = a.x - b.x, dy = a.y - b.y, dz = a.z - b.z, dw = a.w - b.w;
        s += dx * dx + dy * dy + dz * dz + dw * dw;
    }
    s = blockReduceSum(s);
    if (threadIdx.x == 0) dists[blockIdx.x] = s / (float)D;
}

__global__ void final_kernel(const float* __restrict__ dists,
                             const float* __restrict__ within,
                             const float* __restrict__ cross,
                             const float* __restrict__ aug,
                             float* __restrict__ out)
{
    float ce = 0.f, accv = 0.f, uns = 0.f;
    for (int r = threadIdx.x; r < 320; r += 256) {
        const float* dr = dists + r * 20;
        const int y = r / 16;
        float dmin = dr[0];
        int amin = 0;
        float m = -dr[0];
        #pragma unroll
        for (int j = 1; j < 20; ++j) {
            if (dr[j] < dmin) { dmin = dr[j]; amin = j; }
            m = fmaxf(m, -dr[j]);
        }
        float se = 0.f;
        #pragma unroll
        for (int j = 0; j < 20; ++j) se += expf(-dr[j] - m);
        const float lse = m + logf(se);
        ce += dr[y] + lse;
        accv += (amin == y) ? 1.0f : 0.0f;
    }
    for (int i = threadIdx.x; i < 1280; i += 256) uns += within[i] - cross[i];
    for (int i = threadIdx.x; i < 160; i += 256) uns += aug[i];

    ce = blockReduceSum(ce);
    accv = blockReduceSum(accv);
    uns = blockReduceSum(uns);
    if (threadIdx.x == 0) {
        out[0] = ce / 320.0f + uns / 17.0f + 80.0f;   // 0.5 * 160
        out[1] = accv / 320.0f;
    }
}

extern "C" void kernel_launch(void* const* d_in, const int* in_sizes, int n_in,
                              void* d_out, int out_size, void* d_ws, size_t ws_size,
                              hipStream_t stream)
{
    (void)in_sizes; (void)n_in; (void)out_size; (void)ws_size;
    const float* sup = (const float*)d_in[0];
    const float* qry = (const float*)d_in[1];
    const float* K[8]; for (int i = 0; i < 8; ++i) K[i] = (const float*)d_in[2 + i];
    const float* B[8]; for (int i = 0; i < 8; ++i) B[i] = (const float*)d_in[10 + i];
    const float* g1  = (const float*)d_in[18];
    const float* be1 = (const float*)d_in[19];
    const float* g2  = (const float*)d_in[20];
    const float* be2 = (const float*)d_in[21];
    const float* Wm  = (const float*)d_in[22];
    float* out = (float*)d_out;

    // ---- workspace carve-up (~68 MB total) ----
    size_t off = 0;
    auto alloc = [&](size_t bytes) -> void* {
        void* p = (char*)d_ws + off;
        off += (bytes + 255) & ~(size_t)255;
        return p;
    };
    u16*   wf     = (u16*)alloc((size_t)2 * WF_VAR * 2);
    float* btab   = (float*)alloc(256 * 4);
    u16*   s1out  = (u16*)alloc((size_t)800 * 42 * 42 * 16 * 2);
    float* z      = (float*)alloc((size_t)320 * D * 4);
    float* zp     = (float*)alloc((size_t)480 * D * 4);
    float* within = (float*)alloc(1280 * 4);
    float* crossb = (float*)alloc(1280 * 4);
    float* augb   = (float*)alloc(160 * 4);
    float* protos = (float*)alloc((size_t)20 * D * 4);
    float* dist   = (float*)alloc(6400 * 4);

    prep_weights<<<(2 * WF_VAR + 256 + 255) / 256, 256, 0, stream>>>(
        K[0], K[1], K[2], K[3], K[4], K[5], K[6], K[7],
        B[0], B[1], B[2], B[3], B[4], B[5], B[6], B[7],
        Wm, wf, btab);

    stage1_kernel<<<800 * 6, 512, 0, stream>>>(sup, qry, wf, btab, g1, be1, Wm, s1out);
    stage2_kernel<<<1600, 512, 0, stream>>>(s1out, wf, btab, g2, be2, Wm, z, zp);

    pairs_kernel<<<2720, 256, 0, stream>>>(z, within, crossb, augb);
    protos_kernel<<<(20 * D + 255) / 256, 256, 0, stream>>>(zp, protos);
    dists_kernel<<<6400, 256, 0, stream>>>(zp + (size_t)160 * D, protos, dist);
    final_kernel<<<1, 256, 0, stream>>>(dist, within, crossb, augb, out);
}

// Round 9
// 270.124 us; speedup vs baseline: 1.0807x; 1.0807x over previous
//
#include <hip/hip_runtime.h>
#include <math.h>

// ---------------------------------------------------------------------------
// Prototypical network forward on MI355X.
// Round 11: stage1 frozen at the R9/R10 code (194 us, LDS-bound). stage2 conv
// reverted to the verbatim R8 implementation (per-tile magic-div addressing =
// full ILP on ds_read issue, cached raddr[], vmask in read loop, masked
// writes). R10 showed the incremental serial walk -- not the zero-pass -- was
// stage2's regression: the recurrence chains ds_read issue behind VALU deps,
// which stage2's small per-wave workload can't hide.
//   image slots: [0,160) sup | [160,320) sup flipped | [320,800) pro(sup+qry)
// ---------------------------------------------------------------------------

typedef __attribute__((ext_vector_type(8))) short bf16x8;
typedef __attribute__((ext_vector_type(8))) unsigned short u16x8;
typedef __attribute__((ext_vector_type(4))) float f32x4;
typedef unsigned short u16;
typedef unsigned int u32;

#define PIX84 (84 * 84)      // 7056
#define D     (21 * 21 * 16) // 7056
#define WF_LAYER 2560        // u16 per conv2..8 layer: 5 steps * 64 lanes * 8
#define WF_C1 (7 * WF_LAYER) // 17920: offset (u16) of conv1 A-fragments
#define WF_VAR (WF_C1 + 1024) // u16 per variant (plain / Wm-scaled)

__device__ __forceinline__ float bf2f(u16 v) {
    union { u32 i; float f; } c; c.i = ((u32)v) << 16; return c.f;
}
__device__ __forceinline__ u16 f2bf(float f) {
    union { float f; u32 i; } c; c.f = f;
    u32 r = c.i + 0x7fffu + ((c.i >> 16) & 1u);
    return (u16)(r >> 16);
}
// Native bf16 pair conversion: compiler emits v_cvt_pk_bf16_f32 (RNE).
__device__ __forceinline__ u32 pack2(float a, float b) {
    union { __bf16 h[2]; u32 u; } p;
    p.h[0] = (__bf16)a; p.h[1] = (__bf16)b;
    return p.u;
}

// 16B LDS load with only 8B alignment guarantee (ds_read2_b64).
__device__ __forceinline__ bf16x8 ld_bf16x8_a8(const char* p) {
    union { uint2 q[2]; bf16x8 v; } u;
    u.q[0] = *(const uint2*)(p);
    u.q[1] = *(const uint2*)(p + 8);
    return u.v;
}

__device__ __forceinline__ float blockReduceSum(float v) {
    __shared__ float red[8];
    #pragma unroll
    for (int o = 32; o > 0; o >>= 1) v += __shfl_down(v, o, 64);
    const int lane = threadIdx.x & 63, wid = threadIdx.x >> 6;
    __syncthreads();
    if (lane == 0) red[wid] = v;
    __syncthreads();
    float r = 0.f;
    if (threadIdx.x == 0) {
        const int nw = (blockDim.x + 63) >> 6;
        for (int i = 0; i < nw; ++i) r += red[i];
    }
    return r;
}

// Pack conv weights into MFMA A-fragment layout, two variants (v=0 plain,
// v=1 scaled by the layer's Wm factor), plus a bias table [2][8][16] f32
// (same scaling; bias seeds the accumulator in conv layers).
// conv2..8 K=160 mapping: gg=(g>>1) tap table {m / m+5}, ci = (g&1)*8 + j.
// conv1: 2 MFMAs, k = dh*16 + dw*4 + ci (m0: dh 0/1, m1: dh 2).
__global__ void prep_weights(const float* __restrict__ k1, const float* __restrict__ k2,
                             const float* __restrict__ k3, const float* __restrict__ k4,
                             const float* __restrict__ k5, const float* __restrict__ k6,
                             const float* __restrict__ k7, const float* __restrict__ k8,
                             const float* __restrict__ b1, const float* __restrict__ b2,
                             const float* __restrict__ b3, const float* __restrict__ b4,
                             const float* __restrict__ b5, const float* __restrict__ b6,
                             const float* __restrict__ b7, const float* __restrict__ b8,
                             const float* __restrict__ Wm,
                             u16* __restrict__ wf, float* __restrict__ bias_tab)
{
    const int idx = blockIdx.x * 256 + threadIdx.x;
    if (idx < 2 * WF_VAR) {
        const int v = (idx >= WF_VAR) ? 1 : 0;
        const int r0 = idx - v * WF_VAR;
        if (r0 < WF_C1) {
            const int j = r0 & 7, lane = (r0 >> 3) & 63, r = r0 >> 9;
            const int m = r % 5, L = r / 5;
            const float* ks[7] = { k2, k3, k4, k5, k6, k7, k8 };
            const int sidx[7] = { 1, 2, 3, 7, 8, 9, 10 };
            const int co = lane & 15, g = lane >> 4;
            const int gg = g >> 1, h = g & 1;
            const int tap = gg ? (m + 5) : m;
            const int ci = h * 8 + j;
            float val = (tap < 9) ? ks[L][(tap * 16 + ci) * 16 + co] : 0.f;
            if (v) val *= Wm[sidx[L]];
            wf[idx] = f2bf(val);
        } else {
            const int t = r0 - WF_C1;
            const int j = t & 7, lane = (t >> 3) & 63, m = t >> 9;
            const int co = lane & 15, g = lane >> 4;
            const int k = g * 8 + j;
            const int dh  = (m == 0) ? (k >> 4) : 2;
            const int rem = (m == 0) ? (k & 15) : k;
            const int dw = rem >> 2, ci = rem & 3;
            float val = (rem < 12 && ci < 3) ? k1[((dh * 3 + dw) * 3 + ci) * 16 + co] : 0.f;
            if (v) val *= Wm[0];
            wf[idx] = f2bf(val);
        }
    } else if (idx < 2 * WF_VAR + 256) {
        const int t = idx - 2 * WF_VAR;
        const int v = t >> 7, L = (t >> 4) & 7, ch = t & 15;
        const float* Bs[8] = { b1, b2, b3, b4, b5, b6, b7, b8 };
        const int sm[8] = { 0, 1, 2, 3, 7, 8, 9, 10 };
        float val = Bs[L][ch];
        if (v) val *= Wm[sm[L]];
        bias_tab[t] = val;
    }
}

// ---- stage1 conv layer (R9): incremental walk, unconditional writes, ----
// ---- caller-relied row-zero pass for edge strips.                     ----
template <int W, int LW, int MAXT, int HALF>
__device__ __forceinline__ void conv_layer_inc(char* buf, const u16* wfL,
                                               const float4 bv,
                                               int nrows, int v0, int v1,
                                               int lane, int wv)
{
    const int g = lane >> 4, col = lane & 15, gg = g >> 1, h = g & 1;
    bf16x8 wfr[5];
    #pragma unroll
    for (int s = 0; s < 5; ++s) wfr[s] = ((const bf16x8*)wfL)[s * 64 + lane];
    const int NPX = nrows * W;
    const int TC = (NPX + 15) >> 4;
    const int t0 = wv * MAXT;
    const int C0 = h * HALF + (gg ? (LW + 2)     : 0       ) * 16;
    const int C1 = h * HALF + (gg ? (2 * LW)     : 1       ) * 16;
    const int C2 = h * HALF + (gg ? (2 * LW + 1) : 2       ) * 16;
    const int C3 = h * HALF + (gg ? (2 * LW + 2) : LW      ) * 16;
    const int C4 = h * HALF + (gg ? (LW + 2)     : (LW + 1)) * 16;
    const int wb = gg * HALF + h * 8 + 16;

    f32x4 acc[MAXT];
    {
        int px = t0 * 16 + col;
        int j  = px / W;
        int w  = px - j * W;
        int ra = (j * LW + w) * 16;
        #pragma unroll
        for (int u = 0; u < MAXT; ++u) {
            if (t0 + u < TC) {
                const char* rb = buf + ra;
                f32x4 a = { bv.x, bv.y, bv.z, bv.w };
                a = __builtin_amdgcn_mfma_f32_16x16x32_bf16(wfr[0], *(const bf16x8*)(rb + C0), a, 0, 0, 0);
                a = __builtin_amdgcn_mfma_f32_16x16x32_bf16(wfr[1], *(const bf16x8*)(rb + C1), a, 0, 0, 0);
                a = __builtin_amdgcn_mfma_f32_16x16x32_bf16(wfr[2], *(const bf16x8*)(rb + C2), a, 0, 0, 0);
                a = __builtin_amdgcn_mfma_f32_16x16x32_bf16(wfr[3], *(const bf16x8*)(rb + C3), a, 0, 0, 0);
                a = __builtin_amdgcn_mfma_f32_16x16x32_bf16(wfr[4], *(const bf16x8*)(rb + C4), a, 0, 0, 0);
                acc[u] = a;
            }
            const bool wrap = (w + 16) >= W;
            ra += wrap ? (LW + 16 - W) * 16 : 256;
            w  += wrap ? (16 - W) : 16;
        }
    }
    __syncthreads();   // all reads done before any in-place write
    {
        int px = t0 * 16 + col;
        int j  = px / W;
        int w  = px - j * W;
        int ra = (j * LW + w) * 16 + wb;
        #pragma unroll
        for (int u = 0; u < MAXT; ++u) {
            if (t0 + u < TC) {
                const u32 lo = pack2(acc[u][0], acc[u][1]);
                const u32 hi = pack2(acc[u][2], acc[u][3]);
                *(uint2*)(buf + ra) = make_uint2(lo, hi);
            }
            const bool wrap = (w + 16) >= W;
            ra += wrap ? (LW + 16 - W) * 16 : 256;
            w  += wrap ? (16 - W) : 16;
        }
    }
    if (v0 > 0 || v1 < nrows) {   // block-uniform: edge strips only
        __syncthreads();
        const int nzr = v0 + (nrows - v1);
        for (int i = threadIdx.x; i < nzr * LW; i += 512) {
            const int q = i / LW, c = i - q * LW;
            const int r = (q < v0) ? q : (v1 + (q - v0));
            const int P = (r * LW + c) * 16;
            *(uint4*)(buf + P) = make_uint4(0, 0, 0, 0);
            *(uint4*)(buf + HALF + P) = make_uint4(0, 0, 0, 0);
        }
    }
    __syncthreads();
}

// ---- stage2 conv layer (R8 verbatim): per-tile magic-div addressing ----
// ---- (independent addresses -> batched ds_read issue), cached raddr, ----
// ---- vmask in read loop, value-masked writes.                        ----
template <int W, int LW, int MAXT, int HALF>
__device__ __forceinline__ void conv_layer_div(char* buf, const u16* wfL,
                                               const float4 bv,
                                               int nrows, int v0, int v1,
                                               int lane, int wv)
{
    const int g = lane >> 4, col = lane & 15, gg = g >> 1, h = g & 1;
    bf16x8 wfr[5];
    #pragma unroll
    for (int s = 0; s < 5; ++s) wfr[s] = ((const bf16x8*)wfL)[s * 64 + lane];
    const int NPX = nrows * W;
    const int TC = (NPX + 15) >> 4;
    const int t0 = wv * MAXT;
    const int C0 = h * HALF + (gg ? (LW + 2)     : 0       ) * 16;
    const int C1 = h * HALF + (gg ? (2 * LW)     : 1       ) * 16;
    const int C2 = h * HALF + (gg ? (2 * LW + 1) : 2       ) * 16;
    const int C3 = h * HALF + (gg ? (2 * LW + 2) : LW      ) * 16;
    const int C4 = h * HALF + (gg ? (LW + 2)     : (LW + 1)) * 16;
    const int wb = gg * HALF + h * 8 + 16;

    f32x4 acc[MAXT];
    int raddr[MAXT];
    u32 vmask = 0;
    #pragma unroll
    for (int u = 0; u < MAXT; ++u) {
        const int t = t0 + u;
        if (t < TC) {
            const int px = t * 16 + col;
            const int p = (px < NPX) ? px : 0;
            const int j = p / W, w = p - j * W;
            const int ra = (j * LW + w) * 16;
            raddr[u] = ra;
            if ((px < NPX) && (j >= v0) && (j < v1)) vmask |= (1u << u);
            const char* rb = buf + ra;
            f32x4 a = { bv.x, bv.y, bv.z, bv.w };
            a = __builtin_amdgcn_mfma_f32_16x16x32_bf16(wfr[0], *(const bf16x8*)(rb + C0), a, 0, 0, 0);
            a = __builtin_amdgcn_mfma_f32_16x16x32_bf16(wfr[1], *(const bf16x8*)(rb + C1), a, 0, 0, 0);
            a = __builtin_amdgcn_mfma_f32_16x16x32_bf16(wfr[2], *(const bf16x8*)(rb + C2), a, 0, 0, 0);
            a = __builtin_amdgcn_mfma_f32_16x16x32_bf16(wfr[3], *(const bf16x8*)(rb + C3), a, 0, 0, 0);
            a = __builtin_amdgcn_mfma_f32_16x16x32_bf16(wfr[4], *(const bf16x8*)(rb + C4), a, 0, 0, 0);
            acc[u] = a;
        }
    }
    __syncthreads();   // all reads done before any in-place write
    #pragma unroll
    for (int u = 0; u < MAXT; ++u) {
        const int t = t0 + u;
        if (t < TC) {
            const int px = t * 16 + col;
            if (px < NPX) {
                u32 lo = 0, hi = 0;
                if ((vmask >> u) & 1u) {
                    lo = pack2(acc[u][0], acc[u][1]);
                    hi = pack2(acc[u][2], acc[u][3]);
                }
                *(uint2*)(buf + raddr[u] + wb) = make_uint2(lo, hi);
            }
        }
    }
    __syncthreads();
}

// stage1: conv1(MFMA) + conv2/3/4(MFMA) + bn/relu/pool -> s1out (42x42x16 bf16)
// grid: img * 6 strips (7 pooled rows each). Single 20x86 LDS buffer, in-place.
#define HALF1 (20 * 86 * 16 + 16)   // 27536 B
__global__ __launch_bounds__(512) void stage1_kernel(
    const float* __restrict__ sup, const float* __restrict__ qry,
    const u16* __restrict__ wf, const float* __restrict__ bias_tab,
    const float* __restrict__ g1, const float* __restrict__ be1,
    const float* __restrict__ Wm,
    u16* __restrict__ s1out)
{
    __shared__ char buf[2 * HALF1];             // 55,072 B
    __shared__ u16 stag[(22 * 86 + 2) * 4];     // 15,152 B raw input, ch padded to 4
    const int img = blockIdx.x / 6, bb = blockIdx.x % 6;
    const int R0 = 14 * bb;              // base c4-row of this strip
    const int tid = threadIdx.x, lane = tid & 63, wv = tid >> 6;
    const bool pro = img >= 320;

    const float* src;
    bool flip = false;
    if (img < 160) src = sup + (size_t)img * (PIX84 * 3);
    else if (img < 320) { src = sup + (size_t)(img - 160) * (PIX84 * 3); flip = true; }
    else {
        const int m = img - 320;
        src = (m < 160) ? sup + (size_t)m * (PIX84 * 3)
                        : qry + (size_t)(m - 160) * (PIX84 * 3);
    }
    const u16* wfv = wf + (pro ? WF_VAR : 0);
    const float* bt = bias_tab + (pro ? 128 : 0);
    const float pre = pro ? Wm[4] : 1.f, rs = pro ? Wm[5] : 1.f;
    const float post = pro ? Wm[6] : 1.f;

    // zero border columns of conv buffer (rows 0..19, cols 0 & 85)
    for (int i = tid; i < 40; i += 512) {
        const int P = (i >> 1) * 86 + ((i & 1) ? 85 : 0);
        *(uint4*)(buf + P * 16) = make_uint4(0, 0, 0, 0);
        *(uint4*)(buf + HALF1 + P * 16) = make_uint4(0, 0, 0, 0);
    }

    // stage raw input rows R0-4 .. R0+17 as bf16, zero-padded borders.
    for (int p = tid; p < 22 * 86; p += 512) {
        const int r = p / 86, c = p - r * 86;
        const int hin = R0 - 4 + r, win = c - 1;
        u32 lo = 0, hi = 0;
        if ((unsigned)hin < 84u && (unsigned)win < 84u) {
            const int wsrc = flip ? (83 - win) : win;
            const float* ip = src + ((size_t)(hin * 84 + wsrc)) * 3;
            lo = pack2(ip[0], ip[1]);
            hi = pack2(ip[2], 0.f);
        }
        *(uint2*)((char*)stag + (size_t)p * 8) = make_uint2(lo, hi);
    }
    __syncthreads();

    const int g = lane >> 4, col = lane & 15;

    // conv1 via MFMA: 105 tiles (t = wv + 8u), incremental addresses.
    {
        const bf16x8 wA0 = ((const bf16x8*)(wfv + WF_C1))[lane];
        const bf16x8 wA1 = ((const bf16x8*)(wfv + WF_C1))[64 + lane];
        const float4 bv = *(const float4*)(bt + g * 4);   // layer-1 bias (scaled)
        const int off0 = ((g >> 1) * 86 + (g & 1) * 2) * 8;
        const int off1 = (2 * 86 + (g & 1) * 2) * 8;
        const int wbc = (g >> 1) * HALF1 + (g & 1) * 8 + 16;
        int w = wv * 16 + col, j = 0;
        if (w >= 84) { w -= 84; j = 1; }
        int sra = (j * 86 + w) * 8;
        const int trips1 = (112 - wv) >> 3;   // TC=105
        #pragma unroll
        for (int u = 0; u < 14; ++u) {
            if (u < trips1) {
                const bf16x8 B0 = ld_bf16x8_a8((const char*)stag + sra + off0);
                const bf16x8 B1 = ld_bf16x8_a8((const char*)stag + sra + off1);
                f32x4 a = { bv.x, bv.y, bv.z, bv.w };
                a = __builtin_amdgcn_mfma_f32_16x16x32_bf16(wA0, B0, a, 0, 0, 0);
                a = __builtin_amdgcn_mfma_f32_16x16x32_bf16(wA1, B1, a, 0, 0, 0);
                const u32 lo = pack2(a[0], a[1]);
                const u32 hi = pack2(a[2], a[3]);
                *(uint2*)(buf + sra * 2 + wbc) = make_uint2(lo, hi);
            }
            const bool wrap = (w + 44) >= 84;
            sra += wrap ? 1056 : 1040;        // (2*86-40)*8 : (86+44)*8
            w = wrap ? (w - 40) : (w + 44);
        }
    }
    __syncthreads();
    if (R0 == 0 || R0 == 70) {    // conv1 rows outside image -> exact zero
        const int rz = (R0 == 0) ? 0 : 17;
        for (int i = tid; i < 3 * 86; i += 512) {
            const int q = i / 86;
            const int P = ((rz + q) * 86 + (i - q * 86)) * 16;
            *(uint4*)(buf + P) = make_uint4(0, 0, 0, 0);
            *(uint4*)(buf + HALF1 + P) = make_uint4(0, 0, 0, 0);
        }
        __syncthreads();
    }

    const float4 bv2 = *(const float4*)(bt + 16 + g * 4);
    const float4 bv3 = *(const float4*)(bt + 32 + g * 4);
    const float4 bv4 = *(const float4*)(bt + 48 + g * 4);

    // valid-row windows: buf row i after layer L holds conv-row R0-3+L+i.
    conv_layer_inc<84, 86, 12, HALF1>(buf, wfv,                bv2, 18,
                                  (2 - R0 > 0) ? 2 - R0 : 0, (86 - R0 < 18) ? 86 - R0 : 18, lane, wv);
    conv_layer_inc<84, 86, 11, HALF1>(buf, wfv + WF_LAYER,     bv3, 16,
                                  (1 - R0 > 0) ? 1 - R0 : 0, (85 - R0 < 16) ? 85 - R0 : 16, lane, wv);
    conv_layer_inc<84, 86, 10, HALF1>(buf, wfv + 2 * WF_LAYER, bv4, 14,
                                  0,                         (84 - R0 < 14) ? 84 - R0 : 14, lane, wv);

    // monotone pool: o = AR * relu(max(fma(A,mx,B), fma(A,mn,B))) — exact.
    const int hf = tid & 1;      // e&1 == tid&1 (stride 512 even)
    float Ag[8], Bg[8];
    #pragma unroll
    for (int c = 0; c < 8; ++c) {
        const int ch = hf * 8 + c;
        Ag[c] = pre * g1[ch];
        Bg[c] = pre * be1[ch];
    }
    const float AR = post * rs;
    for (int e = tid; e < 7 * 42 * 2; e += 512) {
        const int pc = (e >> 1) % 42, pr = (e >> 1) / 42;
        const char* hb = buf + hf * HALF1;
        const int P0 = (2 * pr) * 86 + (2 * pc + 1);
        const u16x8 v00 = *(const u16x8*)(hb + P0 * 16);
        const u16x8 v01 = *(const u16x8*)(hb + (P0 + 1) * 16);
        const u16x8 v10 = *(const u16x8*)(hb + (P0 + 86) * 16);
        const u16x8 v11 = *(const u16x8*)(hb + (P0 + 87) * 16);
        float o[8];
        #pragma unroll
        for (int c = 0; c < 8; ++c) {
            const float x0 = bf2f(v00[c]), x1 = bf2f(v01[c]);
            const float x2 = bf2f(v10[c]), x3 = bf2f(v11[c]);
            const float mx = fmaxf(fmaxf(fmaxf(x0, x1), x2), x3);
            const float mn = fminf(fminf(fminf(x0, x1), x2), x3);
            const float t1 = fmaf(Ag[c], mx, Bg[c]);
            const float t2 = fmaf(Ag[c], mn, Bg[c]);
            o[c] = AR * fmaxf(0.f, fmaxf(t1, t2));
        }
        uint4 ov;
        ov.x = pack2(o[0], o[1]);
        ov.y = pack2(o[2], o[3]);
        ov.z = pack2(o[4], o[5]);
        ov.w = pack2(o[6], o[7]);
        *(uint4*)(s1out + (size_t)img * 28224 +
                  ((size_t)(7 * bb + pr) * 42 + pc) * 16 + hf * 8) = ov;
    }
}

// stage2: 2 blocks per image (c8 rows [0,22) / [22,42)), stage1-style
// shrinking in-place buffer; conv5..8 + bn + pool -> z/zp (f32).
#define LW2   46
#define NR2   30
#define HALF2 (NR2 * LW2 * 16 + 16)   // 22,096 B
__global__ __launch_bounds__(512) void stage2_kernel(
    const u16* __restrict__ s1in,
    const u16* __restrict__ wf, const float* __restrict__ bias_tab,
    const float* __restrict__ g2, const float* __restrict__ be2,
    const float* __restrict__ Wm,
    float* __restrict__ z, float* __restrict__ zp)
{
    __shared__ char buf[2 * HALF2];   // 44,192 B
    const int img = blockIdx.x >> 1, hb2 = blockIdx.x & 1;
    const int nc8 = hb2 ? 20 : 22;
    const int R0in = hb2 ? 18 : -4;   // s1 row held in buf row 0
    const int tid = threadIdx.x, lane = tid & 63, wv = tid >> 6;
    const bool pro = img >= 320;
    const u16* wfv = wf + (pro ? WF_VAR : 0);
    const float* bt = bias_tab + (pro ? 128 : 0);
    const float pre = pro ? Wm[11] : 1.f, rs = pro ? Wm[12] : 1.f;
    const float post = pro ? (Wm[13] * Wm[14]) : 1.f;

    // load s1 rows R0in .. R0in+29 (zero outside image / border cols)
    const u16* ip = s1in + (size_t)img * 28224;
    for (int i = tid; i < NR2 * 44; i += 512) {
        const int r = i / 44, c = i - r * 44;
        const int gr = R0in + r;
        const int P = r * LW2 + c;
        uint4 w0 = make_uint4(0, 0, 0, 0), w1 = w0;
        if (c >= 1 && c <= 42 && gr >= 0 && gr < 42) {
            const u16* q = ip + ((size_t)(gr * 42 + (c - 1))) * 16;
            w0 = *(const uint4*)q;
            w1 = *(const uint4*)(q + 8);
        }
        *(uint4*)(buf + P * 16) = w0;
        *(uint4*)(buf + HALF2 + P * 16) = w1;
    }
    __syncthreads();

    const int g = lane >> 4;
    const float4 bv5 = *(const float4*)(bt + 64 + g * 4);
    const float4 bv6 = *(const float4*)(bt + 80 + g * 4);
    const float4 bv7 = *(const float4*)(bt + 96 + g * 4);
    const float4 bv8 = *(const float4*)(bt + 112 + g * 4);

    // buf row i after layer L (L=1..4) holds c(4+L) row R0in+i+L.
    {
        const int n1 = nc8 + 6, n2 = nc8 + 4, n3 = nc8 + 2, n4 = nc8;
        int a0, a1;
        a0 = -R0in - 1; if (a0 < 0) a0 = 0; a1 = 41 - R0in; if (a1 > n1) a1 = n1;
        conv_layer_div<42, LW2, 10, HALF2>(buf, wfv + 3 * WF_LAYER, bv5, n1, a0, a1, lane, wv);
        a0 = -R0in - 2; if (a0 < 0) a0 = 0; a1 = 40 - R0in; if (a1 > n2) a1 = n2;
        conv_layer_div<42, LW2, 10, HALF2>(buf, wfv + 4 * WF_LAYER, bv6, n2, a0, a1, lane, wv);
        a0 = -R0in - 3; if (a0 < 0) a0 = 0; a1 = 39 - R0in; if (a1 > n3) a1 = n3;
        conv_layer_div<42, LW2, 10, HALF2>(buf, wfv + 5 * WF_LAYER, bv7, n3, a0, a1, lane, wv);
        a0 = -R0in - 4; if (a0 < 0) a0 = 0; a1 = 38 - R0in; if (a1 > n4) a1 = n4;
        conv_layer_div<42, LW2, 10, HALF2>(buf, wfv + 6 * WF_LAYER, bv8, n4, a0, a1, lane, wv);
    }

    float* outp = pro ? (zp + (size_t)(img - 320) * D) : (z + (size_t)img * D);
    const int hf = tid & 1;
    float Ag[8], Bg[8];
    #pragma unroll
    for (int c = 0; c < 8; ++c) {
        const int ch = hf * 8 + c;
        Ag[c] = pre * g2[ch];
        Bg[c] = pre * be2[ch];
    }
    const float AR = post * rs;
    const int np = nc8 >> 1;
    for (int e = tid; e < np * 21 * 2; e += 512) {
        const int pc = (e >> 1) % 21, pr = (e >> 1) / 21;
        const char* hb = buf + hf * HALF2;
        const int P0 = (2 * pr) * LW2 + (2 * pc + 1);
        const u16x8 v00 = *(const u16x8*)(hb + P0 * 16);
        const u16x8 v01 = *(const u16x8*)(hb + (P0 + 1) * 16);
        const u16x8 v10 = *(const u16x8*)(hb + (P0 + LW2) * 16);
        const u16x8 v11 = *(const u16x8*)(hb + (P0 + LW2 + 1) * 16);
        float o[8];
        #pragma unroll
        for (int c = 0; c < 8; ++c) {
            const float x0 = bf2f(v00[c]), x1 = bf2f(v01[c]);
            const float x2 = bf2f(v10[c]), x3 = bf2f(v11[c]);
            const float mx = fmaxf(fmaxf(fmaxf(x0, x1), x2), x3);
            const float mn = fminf(fminf(fminf(x0, x1), x2), x3);
            const float t1 = fmaf(Ag[c], mx, Bg[c]);
            const float t2 = fmaf(Ag[c], mn, Bg[c]);
            o[c] = AR * fmaxf(0.f, fmaxf(t1, t2));
        }
        float* op = outp + ((size_t)((hb2 * 11 + pr) * 21 + pc)) * 16 + hf * 8;
        *(float4*)op = make_float4(o[0], o[1], o[2], o[3]);
        *(float4*)(op + 4) = make_float4(o[4], o[5], o[6], o[7]);
    }
}

// Pairwise (mean squared distance)^2 over z (320 f32 rows).
__global__ void pairs_kernel(const float* __restrict__ z,
                             float* __restrict__ within, float* __restrict__ cross,
                             float* __restrict__ aug)
{
    const int bid = blockIdx.x;
    const float *u, *v;
    float* dst;
    if (bid < 1280) {
        const int c = bid / 64, i = (bid % 64) / 8, j = bid % 8;
        u = z + (size_t)(c * 8 + i) * D;
        v = z + (size_t)(c * 8 + j) * D;
        dst = within + bid;
    } else if (bid < 2560) {
        const int t = bid - 1280;
        const int c = t / 64, i = (t % 64) / 8, j = t % 8;
        const int c2 = (c + 1) % 20;
        u = z + (size_t)(c * 8 + i) * D;
        v = z + (size_t)(c2 * 8 + j) * D;
        dst = cross + t;
    } else {
        const int t = bid - 2560;
        u = z + (size_t)t * D;
        v = z + (size_t)(160 + t) * D;
        dst = aug + t;
    }
    const float4* u4 = (const float4*)u;
    const float4* v4 = (const float4*)v;
    float s = 0.f;
    for (int d = threadIdx.x; d < D / 4; d += 256) {
        const float4 a = u4[d], b = v4[d];
        const float dx = a.x - b.x, dy = a.y - b.y, dz = a.z - b.z, dw = a.w - b.w;
        s += dx * dx + dy * dy + dz * dz + dw * dw;
    }
    s = blockReduceSum(s);
    if (threadIdx.x == 0) {
        const float m = s / (float)D;
        *dst = m * m;
    }
}

__global__ void protos_kernel(const float* __restrict__ zp, float* __restrict__ protos)
{
    const int idx = blockIdx.x * 256 + threadIdx.x;
    if (idx >= 20 * D) return;
    const int c = idx / D, d = idx % D;
    float s = 0.f;
    #pragma unroll
    for (int i = 0; i < 8; ++i) s += zp[(size_t)(c * 8 + i) * D + d];
    protos[idx] = s * 0.125f;
}

__global__ void dists_kernel(const float* __restrict__ zq, const float* __restrict__ protos,
                             float* __restrict__ dists)
{
    const int q = blockIdx.x / 20, c = blockIdx.x % 20;
    const float4* u4 = (const float4*)(zq + (size_t)q * D);
    const float4* v4 = (const float4*)(protos + (size_t)c * D);
    float s = 0.f;
    for (int d = threadIdx.x; d < D / 4; d += 256) {
        const float4 a = u4[d], b = v4[d];
        const float dx = a.x - b.x, dy = a.y - b.y, dz = a.z - b.z, dw = a.w - b.w;
        s += dx * dx + dy * dy + dz * dz + dw * dw;
    }
    s = blockReduceSum(s);
    if (threadIdx.x == 0) dists[blockIdx.x] = s / (float)D;
}

__global__ void final_kernel(const float* __restrict__ dists,
                             const float* __restrict__ within,
                             const float* __restrict__ cross,
                             const float* __restrict__ aug,
                             float* __restrict__ out)
{
    float ce = 0.f, accv = 0.f, uns = 0.f;
    for (int r = threadIdx.x; r < 320; r += 256) {
        const float* dr = dists + r * 20;
        const int y = r / 16;
        float dmin = dr[0];
        int amin = 0;
        float m = -dr[0];
        #pragma unroll
        for (int j = 1; j < 20; ++j) {
            if (dr[j] < dmin) { dmin = dr[j]; amin = j; }
            m = fmaxf(m, -dr[j]);
        }
        float se = 0.f;
        #pragma unroll
        for (int j = 0; j < 20; ++j) se += expf(-dr[j] - m);
        const float lse = m + logf(se);
        ce += dr[y] + lse;
        accv += (amin == y) ? 1.0f : 0.0f;
    }
    for (int i = threadIdx.x; i < 1280; i += 256) uns += within[i] - cross[i];
    for (int i = threadIdx.x; i < 160; i += 256) uns += aug[i];

    ce = blockReduceSum(ce);
    accv = blockReduceSum(accv);
    uns = blockReduceSum(uns);
    if (threadIdx.x == 0) {
        out[0] = ce / 320.0f + uns / 17.0f + 80.0f;   // 0.5 * 160
        out[1] = accv / 320.0f;
    }
}

extern "C" void kernel_launch(void* const* d_in, const int* in_sizes, int n_in,
                              void* d_out, int out_size, void* d_ws, size_t ws_size,
                              hipStream_t stream)
{
    (void)in_sizes; (void)n_in; (void)out_size; (void)ws_size;
    const float* sup = (const float*)d_in[0];
    const float* qry = (const float*)d_in[1];
    const float* K[8]; for (int i = 0; i < 8; ++i) K[i] = (const float*)d_in[2 + i];
    const float* B[8]; for (int i = 0; i < 8; ++i) B[i] = (const float*)d_in[10 + i];
    const float* g1  = (const float*)d_in[18];
    const float* be1 = (const float*)d_in[19];
    const float* g2  = (const float*)d_in[20];
    const float* be2 = (const float*)d_in[21];
    const float* Wm  = (const float*)d_in[22];
    float* out = (float*)d_out;

    // ---- workspace carve-up (~68 MB total) ----
    size_t off = 0;
    auto alloc = [&](size_t bytes) -> void* {
        void* p = (char*)d_ws + off;
        off += (bytes + 255) & ~(size_t)255;
        return p;
    };
    u16*   wf     = (u16*)alloc((size_t)2 * WF_VAR * 2);
    float* btab   = (float*)alloc(256 * 4);
    u16*   s1out  = (u16*)alloc((size_t)800 * 42 * 42 * 16 * 2);
    float* z      = (float*)alloc((size_t)320 * D * 4);
    float* zp     = (float*)alloc((size_t)480 * D * 4);
    float* within = (float*)alloc(1280 * 4);
    float* crossb = (float*)alloc(1280 * 4);
    float* augb   = (float*)alloc(160 * 4);
    float* protos = (float*)alloc((size_t)20 * D * 4);
    float* dist   = (float*)alloc(6400 * 4);

    prep_weights<<<(2 * WF_VAR + 256 + 255) / 256, 256, 0, stream>>>(
        K[0], K[1], K[2], K[3], K[4], K[5], K[6], K[7],
        B[0], B[1], B[2], B[3], B[4], B[5], B[6], B[7],
        Wm, wf, btab);

    stage1_kernel<<<800 * 6, 512, 0, stream>>>(sup, qry, wf, btab, g1, be1, Wm, s1out);
    stage2_kernel<<<1600, 512, 0, stream>>>(s1out, wf, btab, g2, be2, Wm, z, zp);

    pairs_kernel<<<2720, 256, 0, stream>>>(z, within, crossb, augb);
    protos_kernel<<<(20 * D + 255) / 256, 256, 0, stream>>>(zp, protos);
    dists_kernel<<<6400, 256, 0, stream>>>(zp + (size_t)160 * D, protos, dist);
    final_kernel<<<1, 256, 0, stream>>>(dist, within, crossb, augb, out);
}

// Round 10
// 255.470 us; speedup vs baseline: 1.1427x; 1.0574x over previous
//
#include <hip/hip_runtime.h>
#include <math.h>

// ---------------------------------------------------------------------------
// Prototypical network forward on MI355X.
// Round 12: pro-encoder conv tower eliminated from stage1 via affinity.
// c1..c4 (+scales) are affine => u4(x) = alpha*(v4(x)-v4(0)) + u4(0) exactly,
// alpha = Wm0*Wm1*Wm2*Wm3. A 12-block field pass runs both pipelines on a
// zero image; combine builds H = Wm4*(g1*F + be1), F = u4(0)-alpha*v4(0)
// (image-independent, 226KB bf16, L2-resident). Stage1 now encodes 640
// images (sup+flip+qry) instead of 800: sup blocks emit plain AND pro pools
// (pro = W6*W5*relu(max4(slope*v4 + H)), slope = Wm4*g1*alpha); qry blocks
// emit pro only. Stage2 and tail kernels unchanged (R11 structure).
//   main img slots: [0,160) sup | [160,320) sup flipped | [320,640) qry
//   s1out slots unchanged: plain sup i | flip 160+i | pro-sup 320+i | pro-qry 480+m
// ---------------------------------------------------------------------------

typedef __attribute__((ext_vector_type(8))) short bf16x8;
typedef __attribute__((ext_vector_type(8))) unsigned short u16x8;
typedef __attribute__((ext_vector_type(4))) float f32x4;
typedef unsigned short u16;
typedef unsigned int u32;

#define PIX84 (84 * 84)      // 7056
#define D     (21 * 21 * 16) // 7056
#define WF_LAYER 2560        // u16 per conv2..8 layer: 5 steps * 64 lanes * 8
#define WF_C1 (7 * WF_LAYER) // 17920: offset (u16) of conv1 A-fragments
#define WF_VAR (WF_C1 + 1024) // u16 per variant (plain / Wm-scaled)
#define FPIX  (84 * 84 * 16) // field elements

__device__ __forceinline__ float bf2f(u16 v) {
    union { u32 i; float f; } c; c.i = ((u32)v) << 16; return c.f;
}
__device__ __forceinline__ u16 f2bf(float f) {
    union { float f; u32 i; } c; c.f = f;
    u32 r = c.i + 0x7fffu + ((c.i >> 16) & 1u);
    return (u16)(r >> 16);
}
// Native bf16 pair conversion: compiler emits v_cvt_pk_bf16_f32 (RNE).
__device__ __forceinline__ u32 pack2(float a, float b) {
    union { __bf16 h[2]; u32 u; } p;
    p.h[0] = (__bf16)a; p.h[1] = (__bf16)b;
    return p.u;
}

// 16B LDS load with only 8B alignment guarantee (ds_read2_b64).
__device__ __forceinline__ bf16x8 ld_bf16x8_a8(const char* p) {
    union { uint2 q[2]; bf16x8 v; } u;
    u.q[0] = *(const uint2*)(p);
    u.q[1] = *(const uint2*)(p + 8);
    return u.v;
}

__device__ __forceinline__ float blockReduceSum(float v) {
    __shared__ float red[8];
    #pragma unroll
    for (int o = 32; o > 0; o >>= 1) v += __shfl_down(v, o, 64);
    const int lane = threadIdx.x & 63, wid = threadIdx.x >> 6;
    __syncthreads();
    if (lane == 0) red[wid] = v;
    __syncthreads();
    float r = 0.f;
    if (threadIdx.x == 0) {
        const int nw = (blockDim.x + 63) >> 6;
        for (int i = 0; i < nw; ++i) r += red[i];
    }
    return r;
}

// Pack conv weights into MFMA A-fragment layout, two variants (v=0 plain,
// v=1 scaled by the layer's Wm factor), plus a bias table [2][8][16] f32.
// Variant 1 stage1 weights are used ONLY by the zero-image field pass.
__global__ void prep_weights(const float* __restrict__ k1, const float* __restrict__ k2,
                             const float* __restrict__ k3, const float* __restrict__ k4,
                             const float* __restrict__ k5, const float* __restrict__ k6,
                             const float* __restrict__ k7, const float* __restrict__ k8,
                             const float* __restrict__ b1, const float* __restrict__ b2,
                             const float* __restrict__ b3, const float* __restrict__ b4,
                             const float* __restrict__ b5, const float* __restrict__ b6,
                             const float* __restrict__ b7, const float* __restrict__ b8,
                             const float* __restrict__ Wm,
                             u16* __restrict__ wf, float* __restrict__ bias_tab)
{
    const int idx = blockIdx.x * 256 + threadIdx.x;
    if (idx < 2 * WF_VAR) {
        const int v = (idx >= WF_VAR) ? 1 : 0;
        const int r0 = idx - v * WF_VAR;
        if (r0 < WF_C1) {
            const int j = r0 & 7, lane = (r0 >> 3) & 63, r = r0 >> 9;
            const int m = r % 5, L = r / 5;
            const float* ks[7] = { k2, k3, k4, k5, k6, k7, k8 };
            const int sidx[7] = { 1, 2, 3, 7, 8, 9, 10 };
            const int co = lane & 15, g = lane >> 4;
            const int gg = g >> 1, h = g & 1;
            const int tap = gg ? (m + 5) : m;
            const int ci = h * 8 + j;
            float val = (tap < 9) ? ks[L][(tap * 16 + ci) * 16 + co] : 0.f;
            if (v) val *= Wm[sidx[L]];
            wf[idx] = f2bf(val);
        } else {
            const int t = r0 - WF_C1;
            const int j = t & 7, lane = (t >> 3) & 63, m = t >> 9;
            const int co = lane & 15, g = lane >> 4;
            const int k = g * 8 + j;
            const int dh  = (m == 0) ? (k >> 4) : 2;
            const int rem = (m == 0) ? (k & 15) : k;
            const int dw = rem >> 2, ci = rem & 3;
            float val = (rem < 12 && ci < 3) ? k1[((dh * 3 + dw) * 3 + ci) * 16 + co] : 0.f;
            if (v) val *= Wm[0];
            wf[idx] = f2bf(val);
        }
    } else if (idx < 2 * WF_VAR + 256) {
        const int t = idx - 2 * WF_VAR;
        const int v = t >> 7, L = (t >> 4) & 7, ch = t & 15;
        const float* Bs[8] = { b1, b2, b3, b4, b5, b6, b7, b8 };
        const int sm[8] = { 0, 1, 2, 3, 7, 8, 9, 10 };
        float val = Bs[L][ch];
        if (v) val *= Wm[sm[L]];
        bias_tab[t] = val;
    }
}

// H = Wm4*(g1*(u4(0) - alpha*v4(0)) + be1), stored bf16 [84][84][16].
__global__ void combine_field(const u16* __restrict__ fieldraw,
                              const float* __restrict__ g1, const float* __restrict__ be1,
                              const float* __restrict__ Wm, u16* __restrict__ Hf)
{
    const int idx = blockIdx.x * 256 + threadIdx.x;
    if (idx >= FPIX) return;
    const int ch = idx & 15;
    const float alpha = Wm[0] * Wm[1] * Wm[2] * Wm[3];
    const float v4 = bf2f(fieldraw[idx]);
    const float u4 = bf2f(fieldraw[FPIX + idx]);
    const float F = u4 - alpha * v4;
    Hf[idx] = f2bf(Wm[4] * (g1[ch] * F + be1[ch]));
}

// ---- stage1 conv layer (R9): incremental walk, unconditional writes, ----
// ---- caller-relied row-zero pass for edge strips.                     ----
template <int W, int LW, int MAXT, int HALF>
__device__ __forceinline__ void conv_layer_inc(char* buf, const u16* wfL,
                                               const float4 bv,
                                               int nrows, int v0, int v1,
                                               int lane, int wv)
{
    const int g = lane >> 4, col = lane & 15, gg = g >> 1, h = g & 1;
    bf16x8 wfr[5];
    #pragma unroll
    for (int s = 0; s < 5; ++s) wfr[s] = ((const bf16x8*)wfL)[s * 64 + lane];
    const int NPX = nrows * W;
    const int TC = (NPX + 15) >> 4;
    const int t0 = wv * MAXT;
    const int C0 = h * HALF + (gg ? (LW + 2)     : 0       ) * 16;
    const int C1 = h * HALF + (gg ? (2 * LW)     : 1       ) * 16;
    const int C2 = h * HALF + (gg ? (2 * LW + 1) : 2       ) * 16;
    const int C3 = h * HALF + (gg ? (2 * LW + 2) : LW      ) * 16;
    const int C4 = h * HALF + (gg ? (LW + 2)     : (LW + 1)) * 16;
    const int wb = gg * HALF + h * 8 + 16;

    f32x4 acc[MAXT];
    {
        int px = t0 * 16 + col;
        int j  = px / W;
        int w  = px - j * W;
        int ra = (j * LW + w) * 16;
        #pragma unroll
        for (int u = 0; u < MAXT; ++u) {
            if (t0 + u < TC) {
                const char* rb = buf + ra;
                f32x4 a = { bv.x, bv.y, bv.z, bv.w };
                a = __builtin_amdgcn_mfma_f32_16x16x32_bf16(wfr[0], *(const bf16x8*)(rb + C0), a, 0, 0, 0);
                a = __builtin_amdgcn_mfma_f32_16x16x32_bf16(wfr[1], *(const bf16x8*)(rb + C1), a, 0, 0, 0);
                a = __builtin_amdgcn_mfma_f32_16x16x32_bf16(wfr[2], *(const bf16x8*)(rb + C2), a, 0, 0, 0);
                a = __builtin_amdgcn_mfma_f32_16x16x32_bf16(wfr[3], *(const bf16x8*)(rb + C3), a, 0, 0, 0);
                a = __builtin_amdgcn_mfma_f32_16x16x32_bf16(wfr[4], *(const bf16x8*)(rb + C4), a, 0, 0, 0);
                acc[u] = a;
            }
            const bool wrap = (w + 16) >= W;
            ra += wrap ? (LW + 16 - W) * 16 : 256;
            w  += wrap ? (16 - W) : 16;
        }
    }
    __syncthreads();   // all reads done before any in-place write
    {
        int px = t0 * 16 + col;
        int j  = px / W;
        int w  = px - j * W;
        int ra = (j * LW + w) * 16 + wb;
        #pragma unroll
        for (int u = 0; u < MAXT; ++u) {
            if (t0 + u < TC) {
                const u32 lo = pack2(acc[u][0], acc[u][1]);
                const u32 hi = pack2(acc[u][2], acc[u][3]);
                *(uint2*)(buf + ra) = make_uint2(lo, hi);
            }
            const bool wrap = (w + 16) >= W;
            ra += wrap ? (LW + 16 - W) * 16 : 256;
            w  += wrap ? (16 - W) : 16;
        }
    }
    if (v0 > 0 || v1 < nrows) {   // block-uniform: edge strips only
        __syncthreads();
        const int nzr = v0 + (nrows - v1);
        for (int i = threadIdx.x; i < nzr * LW; i += 512) {
            const int q = i / LW, c = i - q * LW;
            const int r = (q < v0) ? q : (v1 + (q - v0));
            const int P = (r * LW + c) * 16;
            *(uint4*)(buf + P) = make_uint4(0, 0, 0, 0);
            *(uint4*)(buf + HALF + P) = make_uint4(0, 0, 0, 0);
        }
    }
    __syncthreads();
}

// ---- stage2 conv layer (R8 verbatim): per-tile magic-div addressing ----
template <int W, int LW, int MAXT, int HALF>
__device__ __forceinline__ void conv_layer_div(char* buf, const u16* wfL,
                                               const float4 bv,
                                               int nrows, int v0, int v1,
                                               int lane, int wv)
{
    const int g = lane >> 4, col = lane & 15, gg = g >> 1, h = g & 1;
    bf16x8 wfr[5];
    #pragma unroll
    for (int s = 0; s < 5; ++s) wfr[s] = ((const bf16x8*)wfL)[s * 64 + lane];
    const int NPX = nrows * W;
    const int TC = (NPX + 15) >> 4;
    const int t0 = wv * MAXT;
    const int C0 = h * HALF + (gg ? (LW + 2)     : 0       ) * 16;
    const int C1 = h * HALF + (gg ? (2 * LW)     : 1       ) * 16;
    const int C2 = h * HALF + (gg ? (2 * LW + 1) : 2       ) * 16;
    const int C3 = h * HALF + (gg ? (2 * LW + 2) : LW      ) * 16;
    const int C4 = h * HALF + (gg ? (LW + 2)     : (LW + 1)) * 16;
    const int wb = gg * HALF + h * 8 + 16;

    f32x4 acc[MAXT];
    int raddr[MAXT];
    u32 vmask = 0;
    #pragma unroll
    for (int u = 0; u < MAXT; ++u) {
        const int t = t0 + u;
        if (t < TC) {
            const int px = t * 16 + col;
            const int p = (px < NPX) ? px : 0;
            const int j = p / W, w = p - j * W;
            const int ra = (j * LW + w) * 16;
            raddr[u] = ra;
            if ((px < NPX) && (j >= v0) && (j < v1)) vmask |= (1u << u);
            const char* rb = buf + ra;
            f32x4 a = { bv.x, bv.y, bv.z, bv.w };
            a = __builtin_amdgcn_mfma_f32_16x16x32_bf16(wfr[0], *(const bf16x8*)(rb + C0), a, 0, 0, 0);
            a = __builtin_amdgcn_mfma_f32_16x16x32_bf16(wfr[1], *(const bf16x8*)(rb + C1), a, 0, 0, 0);
            a = __builtin_amdgcn_mfma_f32_16x16x32_bf16(wfr[2], *(const bf16x8*)(rb + C2), a, 0, 0, 0);
            a = __builtin_amdgcn_mfma_f32_16x16x32_bf16(wfr[3], *(const bf16x8*)(rb + C3), a, 0, 0, 0);
            a = __builtin_amdgcn_mfma_f32_16x16x32_bf16(wfr[4], *(const bf16x8*)(rb + C4), a, 0, 0, 0);
            acc[u] = a;
        }
    }
    __syncthreads();   // all reads done before any in-place write
    #pragma unroll
    for (int u = 0; u < MAXT; ++u) {
        const int t = t0 + u;
        if (t < TC) {
            const int px = t * 16 + col;
            if (px < NPX) {
                u32 lo = 0, hi = 0;
                if ((vmask >> u) & 1u) {
                    lo = pack2(acc[u][0], acc[u][1]);
                    hi = pack2(acc[u][2], acc[u][3]);
                }
                *(uint2*)(buf + raddr[u] + wb) = make_uint2(lo, hi);
            }
        }
    }
    __syncthreads();
}

// stage1: conv1..4(MFMA, PLAIN weights) + pools -> s1out (42x42x16 bf16)
// grid: img * 6 strips. img = img_base + blockIdx/6:
//   [0,160) sup (plain pool -> slot img; pro pool -> slot 320+img)
//   [160,320) flip (plain pool -> slot img)
//   [320,640) qry (pro pool -> slot 480+(img-320))
//   640/641: zero-image field pass (plain/pro weights), dumps raw c4.
#define HALF1 (20 * 86 * 16 + 16)   // 27536 B
__global__ __launch_bounds__(512) void stage1_kernel(
    const float* __restrict__ sup, const float* __restrict__ qry,
    const u16* __restrict__ wf, const float* __restrict__ bias_tab,
    const float* __restrict__ g1, const float* __restrict__ be1,
    const float* __restrict__ Wm,
    const u16* __restrict__ Hf, u16* __restrict__ fieldraw,
    u16* __restrict__ s1out, int img_base)
{
    __shared__ char buf[2 * HALF1];             // 55,072 B
    __shared__ u16 stag[(22 * 86 + 2) * 4];     // 15,152 B raw input, ch padded to 4
    const int img = img_base + blockIdx.x / 6, bb = blockIdx.x % 6;
    const int R0 = 14 * bb;              // base c4-row of this strip
    const int tid = threadIdx.x, lane = tid & 63, wv = tid >> 6;
    const bool field = img >= 640;
    const int fvar = (img == 641) ? 1 : 0;

    const float* src = sup;
    bool flip = false;
    if (!field) {
        if (img < 160) src = sup + (size_t)img * (PIX84 * 3);
        else if (img < 320) { src = sup + (size_t)(img - 160) * (PIX84 * 3); flip = true; }
        else src = qry + (size_t)(img - 320) * (PIX84 * 3);
    }
    const u16* wfv = wf + fvar * WF_VAR;
    const float* bt = bias_tab + fvar * 128;

    // zero border columns of conv buffer (rows 0..19, cols 0 & 85)
    for (int i = tid; i < 40; i += 512) {
        const int P = (i >> 1) * 86 + ((i & 1) ? 85 : 0);
        *(uint4*)(buf + P * 16) = make_uint4(0, 0, 0, 0);
        *(uint4*)(buf + HALF1 + P * 16) = make_uint4(0, 0, 0, 0);
    }

    // stage raw input rows R0-4 .. R0+17 as bf16, zero-padded borders.
    for (int p = tid; p < 22 * 86; p += 512) {
        const int r = p / 86, c = p - r * 86;
        const int hin = R0 - 4 + r, win = c - 1;
        u32 lo = 0, hi = 0;
        if (!field && (unsigned)hin < 84u && (unsigned)win < 84u) {
            const int wsrc = flip ? (83 - win) : win;
            const float* ip = src + ((size_t)(hin * 84 + wsrc)) * 3;
            lo = pack2(ip[0], ip[1]);
            hi = pack2(ip[2], 0.f);
        }
        *(uint2*)((char*)stag + (size_t)p * 8) = make_uint2(lo, hi);
    }
    __syncthreads();

    const int g = lane >> 4, col = lane & 15;

    // conv1 via MFMA: 105 tiles (t = wv + 8u), incremental addresses.
    {
        const bf16x8 wA0 = ((const bf16x8*)(wfv + WF_C1))[lane];
        const bf16x8 wA1 = ((const bf16x8*)(wfv + WF_C1))[64 + lane];
        const float4 bv = *(const float4*)(bt + g * 4);   // layer-1 bias
        const int off0 = ((g >> 1) * 86 + (g & 1) * 2) * 8;
        const int off1 = (2 * 86 + (g & 1) * 2) * 8;
        const int wbc = (g >> 1) * HALF1 + (g & 1) * 8 + 16;
        int w = wv * 16 + col, j = 0;
        if (w >= 84) { w -= 84; j = 1; }
        int sra = (j * 86 + w) * 8;
        const int trips1 = (112 - wv) >> 3;   // TC=105
        #pragma unroll
        for (int u = 0; u < 14; ++u) {
            if (u < trips1) {
                const bf16x8 B0 = ld_bf16x8_a8((const char*)stag + sra + off0);
                const bf16x8 B1 = ld_bf16x8_a8((const char*)stag + sra + off1);
                f32x4 a = { bv.x, bv.y, bv.z, bv.w };
                a = __builtin_amdgcn_mfma_f32_16x16x32_bf16(wA0, B0, a, 0, 0, 0);
                a = __builtin_amdgcn_mfma_f32_16x16x32_bf16(wA1, B1, a, 0, 0, 0);
                const u32 lo = pack2(a[0], a[1]);
                const u32 hi = pack2(a[2], a[3]);
                *(uint2*)(buf + sra * 2 + wbc) = make_uint2(lo, hi);
            }
            const bool wrap = (w + 44) >= 84;
            sra += wrap ? 1056 : 1040;        // (2*86-40)*8 : (86+44)*8
            w = wrap ? (w - 40) : (w + 44);
        }
    }
    __syncthreads();
    if (R0 == 0 || R0 == 70) {    // conv1 rows outside image -> exact zero
        const int rz = (R0 == 0) ? 0 : 17;
        for (int i = tid; i < 3 * 86; i += 512) {
            const int q = i / 86;
            const int P = ((rz + q) * 86 + (i - q * 86)) * 16;
            *(uint4*)(buf + P) = make_uint4(0, 0, 0, 0);
            *(uint4*)(buf + HALF1 + P) = make_uint4(0, 0, 0, 0);
        }
        __syncthreads();
    }

    const float4 bv2 = *(const float4*)(bt + 16 + g * 4);
    const float4 bv3 = *(const float4*)(bt + 32 + g * 4);
    const float4 bv4 = *(const float4*)(bt + 48 + g * 4);

    // valid-row windows: buf row i after layer L holds conv-row R0-3+L+i.
    conv_layer_inc<84, 86, 12, HALF1>(buf, wfv,                bv2, 18,
                                  (2 - R0 > 0) ? 2 - R0 : 0, (86 - R0 < 18) ? 86 - R0 : 18, lane, wv);
    conv_layer_inc<84, 86, 11, HALF1>(buf, wfv + WF_LAYER,     bv3, 16,
                                  (1 - R0 > 0) ? 1 - R0 : 0, (85 - R0 < 16) ? 85 - R0 : 16, lane, wv);
    conv_layer_inc<84, 86, 10, HALF1>(buf, wfv + 2 * WF_LAYER, bv4, 14,
                                  0,                         (84 - R0 < 14) ? 84 - R0 : 14, lane, wv);

    if (field) {
        // dump raw c4 (rows R0..R0+13) for the zero-image field pass
        u16* fr = fieldraw + (size_t)fvar * FPIX;
        for (int e = tid; e < 14 * 84 * 2; e += 512) {
            const int hf2 = e & 1;
            const int c = (e >> 1) % 84, r = (e >> 1) / 84;
            const u16x8 v = *(const u16x8*)(buf + hf2 * HALF1 + (r * 86 + c + 1) * 16);
            *(u16x8*)(fr + ((size_t)(R0 + r) * 84 + c) * 16 + hf2 * 8) = v;
        }
        return;
    }

    const int hf = tid & 1;      // e&1 == tid&1 (stride 512 even)

    // plain pool (sup + flip): o = relu(max(fma(g,mx,be), fma(g,mn,be)))
    if (img < 320) {
        float Ag[8], Bg[8];
        #pragma unroll
        for (int c = 0; c < 8; ++c) {
            const int ch = hf * 8 + c;
            Ag[c] = g1[ch];
            Bg[c] = be1[ch];
        }
        for (int e = tid; e < 7 * 42 * 2; e += 512) {
            const int pc = (e >> 1) % 42, pr = (e >> 1) / 42;
            const char* hb = buf + hf * HALF1;
            const int P0 = (2 * pr) * 86 + (2 * pc + 1);
            const u16x8 v00 = *(const u16x8*)(hb + P0 * 16);
            const u16x8 v01 = *(const u16x8*)(hb + (P0 + 1) * 16);
            const u16x8 v10 = *(const u16x8*)(hb + (P0 + 86) * 16);
            const u16x8 v11 = *(const u16x8*)(hb + (P0 + 87) * 16);
            float o[8];
            #pragma unroll
            for (int c = 0; c < 8; ++c) {
                const float x0 = bf2f(v00[c]), x1 = bf2f(v01[c]);
                const float x2 = bf2f(v10[c]), x3 = bf2f(v11[c]);
                const float mx = fmaxf(fmaxf(fmaxf(x0, x1), x2), x3);
                const float mn = fminf(fminf(fminf(x0, x1), x2), x3);
                const float t1 = fmaf(Ag[c], mx, Bg[c]);
                const float t2 = fmaf(Ag[c], mn, Bg[c]);
                o[c] = fmaxf(0.f, fmaxf(t1, t2));
            }
            uint4 ov;
            ov.x = pack2(o[0], o[1]);
            ov.y = pack2(o[2], o[3]);
            ov.z = pack2(o[4], o[5]);
            ov.w = pack2(o[6], o[7]);
            *(uint4*)(s1out + (size_t)img * 28224 +
                      ((size_t)(7 * bb + pr) * 42 + pc) * 16 + hf * 8) = ov;
        }
    }

    // pro pool (sup + qry): o = W6*W5 * relu(max4(slope*v4 + H))
    if (img < 160 || img >= 320) {
        const int slot = (img < 160) ? (320 + img) : (480 + (img - 320));
        const float alpha = Wm[0] * Wm[1] * Wm[2] * Wm[3];
        const float W65 = Wm[6] * Wm[5];
        float Sg[8];
        #pragma unroll
        for (int c = 0; c < 8; ++c) Sg[c] = Wm[4] * g1[hf * 8 + c] * alpha;
        for (int e = tid; e < 7 * 42 * 2; e += 512) {
            const int pc = (e >> 1) % 42, pr = (e >> 1) / 42;
            const char* hb = buf + hf * HALF1;
            const int P0 = (2 * pr) * 86 + (2 * pc + 1);
            const u16x8 v00 = *(const u16x8*)(hb + P0 * 16);
            const u16x8 v01 = *(const u16x8*)(hb + (P0 + 1) * 16);
            const u16x8 v10 = *(const u16x8*)(hb + (P0 + 86) * 16);
            const u16x8 v11 = *(const u16x8*)(hb + (P0 + 87) * 16);
            const u16* hp = Hf + (((size_t)(R0 + 2 * pr)) * 84 + 2 * pc) * 16 + hf * 8;
            const u16x8 h00 = *(const u16x8*)(hp);
            const u16x8 h01 = *(const u16x8*)(hp + 16);
            const u16x8 h10 = *(const u16x8*)(hp + 84 * 16);
            const u16x8 h11 = *(const u16x8*)(hp + 84 * 16 + 16);
            float o[8];
            #pragma unroll
            for (int c = 0; c < 8; ++c) {
                const float t0v = fmaf(Sg[c], bf2f(v00[c]), bf2f(h00[c]));
                const float t1v = fmaf(Sg[c], bf2f(v01[c]), bf2f(h01[c]));
                const float t2v = fmaf(Sg[c], bf2f(v10[c]), bf2f(h10[c]));
                const float t3v = fmaf(Sg[c], bf2f(v11[c]), bf2f(h11[c]));
                const float mx = fmaxf(fmaxf(fmaxf(t0v, t1v), t2v), t3v);
                o[c] = W65 * fmaxf(0.f, mx);
            }
            uint4 ov;
            ov.x = pack2(o[0], o[1]);
            ov.y = pack2(o[2], o[3]);
            ov.z = pack2(o[4], o[5]);
            ov.w = pack2(o[6], o[7]);
            *(uint4*)(s1out + (size_t)slot * 28224 +
                      ((size_t)(7 * bb + pr) * 42 + pc) * 16 + hf * 8) = ov;
        }
    }
}

// stage2: 2 blocks per image (c8 rows [0,22) / [22,42)), stage1-style
// shrinking in-place buffer; conv5..8 + bn + pool -> z/zp (f32).
#define LW2   46
#define NR2   30
#define HALF2 (NR2 * LW2 * 16 + 16)   // 22,096 B
__global__ __launch_bounds__(512) void stage2_kernel(
    const u16* __restrict__ s1in,
    const u16* __restrict__ wf, const float* __restrict__ bias_tab,
    const float* __restrict__ g2, const float* __restrict__ be2,
    const float* __restrict__ Wm,
    float* __restrict__ z, float* __restrict__ zp)
{
    __shared__ char buf[2 * HALF2];   // 44,192 B
    const int img = blockIdx.x >> 1, hb2 = blockIdx.x & 1;
    const int nc8 = hb2 ? 20 : 22;
    const int R0in = hb2 ? 18 : -4;   // s1 row held in buf row 0
    const int tid = threadIdx.x, lane = tid & 63, wv = tid >> 6;
    const bool pro = img >= 320;
    const u16* wfv = wf + (pro ? WF_VAR : 0);
    const float* bt = bias_tab + (pro ? 128 : 0);
    const float pre = pro ? Wm[11] : 1.f, rs = pro ? Wm[12] : 1.f;
    const float post = pro ? (Wm[13] * Wm[14]) : 1.f;

    // load s1 rows R0in .. R0in+29 (zero outside image / border cols)
    const u16* ip = s1in + (size_t)img * 28224;
    for (int i = tid; i < NR2 * 44; i += 512) {
        const int r = i / 44, c = i - r * 44;
        const int gr = R0in + r;
        const int P = r * LW2 + c;
        uint4 w0 = make_uint4(0, 0, 0, 0), w1 = w0;
        if (c >= 1 && c <= 42 && gr >= 0 && gr < 42) {
            const u16* q = ip + ((size_t)(gr * 42 + (c - 1))) * 16;
            w0 = *(const uint4*)q;
            w1 = *(const uint4*)(q + 8);
        }
        *(uint4*)(buf + P * 16) = w0;
        *(uint4*)(buf + HALF2 + P * 16) = w1;
    }
    __syncthreads();

    const int g = lane >> 4;
    const float4 bv5 = *(const float4*)(bt + 64 + g * 4);
    const float4 bv6 = *(const float4*)(bt + 80 + g * 4);
    const float4 bv7 = *(const float4*)(bt + 96 + g * 4);
    const float4 bv8 = *(const float4*)(bt + 112 + g * 4);

    // buf row i after layer L (L=1..4) holds c(4+L) row R0in+i+L.
    {
        const int n1 = nc8 + 6, n2 = nc8 + 4, n3 = nc8 + 2, n4 = nc8;
        int a0, a1;
        a0 = -R0in - 1; if (a0 < 0) a0 = 0; a1 = 41 - R0in; if (a1 > n1) a1 = n1;
        conv_layer_div<42, LW2, 10, HALF2>(buf, wfv + 3 * WF_LAYER, bv5, n1, a0, a1, lane, wv);
        a0 = -R0in - 2; if (a0 < 0) a0 = 0; a1 = 40 - R0in; if (a1 > n2) a1 = n2;
        conv_layer_div<42, LW2, 10, HALF2>(buf, wfv + 4 * WF_LAYER, bv6, n2, a0, a1, lane, wv);
        a0 = -R0in - 3; if (a0 < 0) a0 = 0; a1 = 39 - R0in; if (a1 > n3) a1 = n3;
        conv_layer_div<42, LW2, 10, HALF2>(buf, wfv + 5 * WF_LAYER, bv7, n3, a0, a1, lane, wv);
        a0 = -R0in - 4; if (a0 < 0) a0 = 0; a1 = 38 - R0in; if (a1 > n4) a1 = n4;
        conv_layer_div<42, LW2, 10, HALF2>(buf, wfv + 6 * WF_LAYER, bv8, n4, a0, a1, lane, wv);
    }

    float* outp = pro ? (zp + (size_t)(img - 320) * D) : (z + (size_t)img * D);
    const int hf = tid & 1;
    float Ag[8], Bg[8];
    #pragma unroll
    for (int c = 0; c < 8; ++c) {
        const int ch = hf * 8 + c;
        Ag[c] = pre * g2[ch];
        Bg[c] = pre * be2[ch];
    }
    const float AR = post * rs;
    const int np = nc8 >> 1;
    for (int e = tid; e < np * 21 * 2; e += 512) {
        const int pc = (e >> 1) % 21, pr = (e >> 1) / 21;
        const char* hb = buf + hf * HALF2;
        const int P0 = (2 * pr) * LW2 + (2 * pc + 1);
        const u16x8 v00 = *(const u16x8*)(hb + P0 * 16);
        const u16x8 v01 = *(const u16x8*)(hb + (P0 + 1) * 16);
        const u16x8 v10 = *(const u16x8*)(hb + (P0 + LW2) * 16);
        const u16x8 v11 = *(const u16x8*)(hb + (P0 + LW2 + 1) * 16);
        float o[8];
        #pragma unroll
        for (int c = 0; c < 8; ++c) {
            const float x0 = bf2f(v00[c]), x1 = bf2f(v01[c]);
            const float x2 = bf2f(v10[c]), x3 = bf2f(v11[c]);
            const float mx = fmaxf(fmaxf(fmaxf(x0, x1), x2), x3);
            const float mn = fminf(fminf(fminf(x0, x1), x2), x3);
            const float t1 = fmaf(Ag[c], mx, Bg[c]);
            const float t2 = fmaf(Ag[c], mn, Bg[c]);
            o[c] = AR * fmaxf(0.f, fmaxf(t1, t2));
        }
        float* op = outp + ((size_t)((hb2 * 11 + pr) * 21 + pc)) * 16 + hf * 8;
        *(float4*)op = make_float4(o[0], o[1], o[2], o[3]);
        *(float4*)(op + 4) = make_float4(o[4], o[5], o[6], o[7]);
    }
}

// Pairwise (mean squared distance)^2 over z (320 f32 rows).
__global__ void pairs_kernel(const float* __restrict__ z,
                             float* __restrict__ within, float* __restrict__ cross,
                             float* __restrict__ aug)
{
    const int bid = blockIdx.x;
    const float *u, *v;
    float* dst;
    if (bid < 1280) {
        const int c = bid / 64, i = (bid % 64) / 8, j = bid % 8;
        u = z + (size_t)(c * 8 + i) * D;
        v = z + (size_t)(c * 8 + j) * D;
        dst = within + bid;
    } else if (bid < 2560) {
        const int t = bid - 1280;
        const int c = t / 64, i = (t % 64) / 8, j = t % 8;
        const int c2 = (c + 1) % 20;
        u = z + (size_t)(c * 8 + i) * D;
        v = z + (size_t)(c2 * 8 + j) * D;
        dst = cross + t;
    } else {
        const int t = bid - 2560;
        u = z + (size_t)t * D;
        v = z + (size_t)(160 + t) * D;
        dst = aug + t;
    }
    const float4* u4 = (const float4*)u;
    const float4* v4 = (const float4*)v;
    float s = 0.f;
    for (int d = threadIdx.x; d < D / 4; d += 256) {
        const float4 a = u4[d], b = v4[d];
        const float dx = a.x - b.x, dy = a.y - b.y, dz = a.z - b.z, dw = a.w - b.w;
        s += dx * dx + dy * dy + dz * dz + dw * dw;
    }
    s = blockReduceSum(s);
    if (threadIdx.x == 0) {
        const float m = s / (float)D;
        *dst = m * m;
    }
}

__global__ void protos_kernel(const float* __restrict__ zp, float* __restrict__ protos)
{
    const int idx = blockIdx.x * 256 + threadIdx.x;
    if (idx >= 20 * D) return;
    const int c = idx / D, d = idx % D;
    float s = 0.f;
    #pragma unroll
    for (int i = 0; i < 8; ++i) s += zp[(size_t)(c * 8 + i) * D + d];
    protos[idx] = s * 0.125f;
}

__global__ void dists_kernel(const float* __restrict__ zq, const float* __restrict__ protos,
                             float* __restrict__ dists)
{
    const int q = blockIdx.x / 20, c = blockIdx.x % 20;
    const float4* u4 = (const float4*)(zq + (size_t)q * D);
    const float4* v4 = (const float4*)(protos + (size_t)c * D);
    float s = 0.f;
    for (int d = threadIdx.x; d < D / 4; d += 256) {
        const float4 a = u4[d], b = v4[d];
        const float dx = a.x - b.x, dy = a.y - b.y, dz = a.z - b.z, dw = a.w - b.w;
        s += dx * dx + dy * dy + dz * dz + dw * dw;
    }
    s = blockReduceSum(s);
    if (threadIdx.x == 0) dists[blockIdx.x] = s / (float)D;
}

__global__ void final_kernel(const float* __restrict__ dists,
                             const float* __restrict__ within,
                             const float* __restrict__ cross,
                             const float* __restrict__ aug,
                             float* __restrict__ out)
{
    float ce = 0.f, accv = 0.f, uns = 0.f;
    for (int r = threadIdx.x; r < 320; r += 256) {
        const float* dr = dists + r * 20;
        const int y = r / 16;
        float dmin = dr[0];
        int amin = 0;
        float m = -dr[0];
        #pragma unroll
        for (int j = 1; j < 20; ++j) {
            if (dr[j] < dmin) { dmin = dr[j]; amin = j; }
            m = fmaxf(m, -dr[j]);
        }
        float se = 0.f;
        #pragma unroll
        for (int j = 0; j < 20; ++j) se += expf(-dr[j] - m);
        const float lse = m + logf(se);
        ce += dr[y] + lse;
        accv += (amin == y) ? 1.0f : 0.0f;
    }
    for (int i = threadIdx.x; i < 1280; i += 256) uns += within[i] - cross[i];
    for (int i = threadIdx.x; i < 160; i += 256) uns += aug[i];

    ce = blockReduceSum(ce);
    accv = blockReduceSum(accv);
    uns = blockReduceSum(uns);
    if (threadIdx.x == 0) {
        out[0] = ce / 320.0f + uns / 17.0f + 80.0f;   // 0.5 * 160
        out[1] = accv / 320.0f;
    }
}

extern "C" void kernel_launch(void* const* d_in, const int* in_sizes, int n_in,
                              void* d_out, int out_size, void* d_ws, size_t ws_size,
                              hipStream_t stream)
{
    (void)in_sizes; (void)n_in; (void)out_size; (void)ws_size;
    const float* sup = (const float*)d_in[0];
    const float* qry = (const float*)d_in[1];
    const float* K[8]; for (int i = 0; i < 8; ++i) K[i] = (const float*)d_in[2 + i];
    const float* B[8]; for (int i = 0; i < 8; ++i) B[i] = (const float*)d_in[10 + i];
    const float* g1  = (const float*)d_in[18];
    const float* be1 = (const float*)d_in[19];
    const float* g2  = (const float*)d_in[20];
    const float* be2 = (const float*)d_in[21];
    const float* Wm  = (const float*)d_in[22];
    float* out = (float*)d_out;

    // ---- workspace carve-up (~68 MB total) ----
    size_t off = 0;
    auto alloc = [&](size_t bytes) -> void* {
        void* p = (char*)d_ws + off;
        off += (bytes + 255) & ~(size_t)255;
        return p;
    };
    u16*   wf     = (u16*)alloc((size_t)2 * WF_VAR * 2);
    float* btab   = (float*)alloc(256 * 4);
    u16*   fraw   = (u16*)alloc((size_t)2 * FPIX * 2);
    u16*   Hf     = (u16*)alloc((size_t)FPIX * 2);
    u16*   s1out  = (u16*)alloc((size_t)800 * 42 * 42 * 16 * 2);
    float* z      = (float*)alloc((size_t)320 * D * 4);
    float* zp     = (float*)alloc((size_t)480 * D * 4);
    float* within = (float*)alloc(1280 * 4);
    float* crossb = (float*)alloc(1280 * 4);
    float* augb   = (float*)alloc(160 * 4);
    float* protos = (float*)alloc((size_t)20 * D * 4);
    float* dist   = (float*)alloc(6400 * 4);

    prep_weights<<<(2 * WF_VAR + 256 + 255) / 256, 256, 0, stream>>>(
        K[0], K[1], K[2], K[3], K[4], K[5], K[6], K[7],
        B[0], B[1], B[2], B[3], B[4], B[5], B[6], B[7],
        Wm, wf, btab);

    // field pass: zero image through plain (img 640) and pro (img 641) towers
    stage1_kernel<<<12, 512, 0, stream>>>(sup, qry, wf, btab, g1, be1, Wm,
                                          Hf, fraw, s1out, 640);
    combine_field<<<(FPIX + 255) / 256, 256, 0, stream>>>(fraw, g1, be1, Wm, Hf);

    stage1_kernel<<<640 * 6, 512, 0, stream>>>(sup, qry, wf, btab, g1, be1, Wm,
                                               Hf, fraw, s1out, 0);
    stage2_kernel<<<1600, 512, 0, stream>>>(s1out, wf, btab, g2, be2, Wm, z, zp);

    pairs_kernel<<<2720, 256, 0, stream>>>(z, within, crossb, augb);
    protos_kernel<<<(20 * D + 255) / 256, 256, 0, stream>>>(zp, protos);
    dists_kernel<<<6400, 256, 0, stream>>>(zp + (size_t)160 * D, protos, dist);
    final_kernel<<<1, 256, 0, stream>>>(dist, within, crossb, augb, out);
}